// Round 2
// baseline (2595.240 us; speedup 1.0000x reference)
//
#include <hip/hip_runtime.h>
#include <hip/hip_bf16.h>
#include <math.h>

typedef __hip_bfloat16 bf16;

__device__ __forceinline__ float b2f(bf16 v) { return __bfloat162float(v); }
__device__ __forceinline__ bf16 f2b(float f) { return __float2bfloat16(f); }

// ---------------------------------------------------------------------------
// K1: LayerNorm1 + window partition (zero pad) -> xw (9800 x 768) bf16
// x is fp32 (B=2,64,64,768)
// ---------------------------------------------------------------------------
__launch_bounds__(256)
__global__ void ln1_window_kernel(const float* __restrict__ x,
                                  const float* __restrict__ wgt,
                                  const float* __restrict__ bia,
                                  bf16* __restrict__ xw)
{
    int blk = blockIdx.x;              // 0..9799
    int bw = blk / 196, n = blk % 196;
    int bb = bw / 25, wq = bw % 25;
    int wh = wq / 5, ww = wq % 5;
    int i = n / 14, j = n % 14;
    int r = wh * 14 + i, cl = ww * 14 + j;
    bf16* out = xw + (size_t)blk * 768;
    int tid = threadIdx.x;
    if (r >= 64 || cl >= 64) {         // padded token -> zeros (uniform branch)
        #pragma unroll
        for (int t = 0; t < 3; t++) out[tid + t * 256] = f2b(0.0f);
        return;
    }
    const float* xin = x + (((size_t)bb * 64 + r) * 64 + cl) * 768;
    float v[3]; float s = 0.f, ss = 0.f;
    #pragma unroll
    for (int t = 0; t < 3; t++) {
        float f = xin[tid + t * 256];
        v[t] = f; s += f; ss += f * f;
    }
    #pragma unroll
    for (int o = 32; o > 0; o >>= 1) { s += __shfl_xor(s, o); ss += __shfl_xor(ss, o); }
    __shared__ float red[8];
    int w = tid >> 6, lane = tid & 63;
    if (lane == 0) { red[w] = s; red[4 + w] = ss; }
    __syncthreads();
    s  = red[0] + red[1] + red[2] + red[3];
    ss = red[4] + red[5] + red[6] + red[7];
    float mu = s * (1.0f / 768.0f);
    float var = ss * (1.0f / 768.0f) - mu * mu;
    float rs = rsqrtf(var + 1e-5f);
    #pragma unroll
    for (int t = 0; t < 3; t++) {
        int c = tid + t * 256;
        out[c] = f2b((v[t] - mu) * rs * wgt[c] + bia[c]);
    }
}

// ---------------------------------------------------------------------------
// K5: LayerNorm2 on y (f32, 8192 x 768) -> xn2 bf16
// ---------------------------------------------------------------------------
__launch_bounds__(256)
__global__ void ln2_kernel(const float* __restrict__ y,
                           const float* __restrict__ wgt,
                           const float* __restrict__ bia,
                           bf16* __restrict__ xn2)
{
    int blk = blockIdx.x;              // 0..8191
    const float* yin = y + (size_t)blk * 768;
    bf16* out = xn2 + (size_t)blk * 768;
    int tid = threadIdx.x;
    float v[3]; float s = 0.f, ss = 0.f;
    #pragma unroll
    for (int t = 0; t < 3; t++) {
        float f = yin[tid + t * 256];
        v[t] = f; s += f; ss += f * f;
    }
    #pragma unroll
    for (int o = 32; o > 0; o >>= 1) { s += __shfl_xor(s, o); ss += __shfl_xor(ss, o); }
    __shared__ float red[8];
    int w = tid >> 6, lane = tid & 63;
    if (lane == 0) { red[w] = s; red[4 + w] = ss; }
    __syncthreads();
    s  = red[0] + red[1] + red[2] + red[3];
    ss = red[4] + red[5] + red[6] + red[7];
    float mu = s * (1.0f / 768.0f);
    float var = ss * (1.0f / 768.0f) - mu * mu;
    float rs = rsqrtf(var + 1e-5f);
    #pragma unroll
    for (int t = 0; t < 3; t++) {
        int c = tid + t * 256;
        out[c] = f2b((v[t] - mu) * rs * wgt[c] + bia[c]);
    }
}

// ---------------------------------------------------------------------------
// Shared tiled GEMM: C = A(MxK,bf16) @ W(KxN,fp32) + bias(fp32), fp32 VALU acc.
// BM=BN=64, BK=32, 256 threads, 4x4 per thread.
//  EPI 0: store bf16 C                        (qkv)
//  EPI 1: window-unpartition+crop, y = x + C  (proj, f32 y out)
//  EPI 2: exact GELU, store bf16              (fc1)
//  EPI 3: outf = yres + C, store f32          (fc2 -> d_out)
// ---------------------------------------------------------------------------
template<int EPI>
__launch_bounds__(256)
__global__ void gemm_kernel(const bf16* __restrict__ A,
                            const float* __restrict__ W,
                            const float* __restrict__ bias,
                            bf16* __restrict__ outb,
                            float* __restrict__ outf,
                            const float* __restrict__ xres,
                            const float* __restrict__ yres,
                            int M, int N, int K)
{
    __shared__ float As[32][68];   // A^T tile: As[k][m]
    __shared__ float Bs[32][68];   // Bs[k][n]
    int tid = threadIdx.x;
    int tx = tid & 15, ty = tid >> 4;
    int tm = blockIdx.y * 64, tn = blockIdx.x * 64;
    float c[4][4] = {};

    int am = tid >> 2;            // 0..63 row in tile
    int ak = (tid & 3) * 8;       // 0,8,16,24
    int bk = tid >> 3;            // 0..31
    int bn = (tid & 7) * 8;       // 0..56
    int gm_a = tm + am;

    for (int k0 = 0; k0 < K; k0 += 32) {
        // A: 8 bf16 per thread (16B)
        uint4 rawa = make_uint4(0u, 0u, 0u, 0u);
        if (gm_a < M) rawa = *(const uint4*)(A + (size_t)gm_a * K + k0 + ak);
        // B: 8 fp32 per thread (two float4)
        const float* wp = W + (size_t)(k0 + bk) * N + tn + bn;
        float4 wb0 = *(const float4*)(wp);
        float4 wb1 = *(const float4*)(wp + 4);
        {
            const unsigned* rw = (const unsigned*)&rawa;
            #pragma unroll
            for (int s = 0; s < 4; s++) {
                unsigned u = rw[s];
                As[ak + 2 * s][am]     = __uint_as_float(u << 16);
                As[ak + 2 * s + 1][am] = __uint_as_float(u & 0xffff0000u);
            }
        }
        *(float4*)&Bs[bk][bn]     = wb0;
        *(float4*)&Bs[bk][bn + 4] = wb1;
        __syncthreads();
        #pragma unroll
        for (int kk = 0; kk < 32; kk++) {
            float4 a4 = *(const float4*)&As[kk][ty * 4];
            float4 b4 = *(const float4*)&Bs[kk][tx * 4];
            float av[4] = {a4.x, a4.y, a4.z, a4.w};
            float bv[4] = {b4.x, b4.y, b4.z, b4.w};
            #pragma unroll
            for (int i = 0; i < 4; i++)
                #pragma unroll
                for (int j = 0; j < 4; j++)
                    c[i][j] += av[i] * bv[j];
        }
        __syncthreads();
    }

    int row0 = tm + ty * 4;
    int col0 = tn + tx * 4;
    float bv[4];
    #pragma unroll
    for (int j = 0; j < 4; j++) bv[j] = bias[col0 + j];

    #pragma unroll
    for (int i = 0; i < 4; i++) {
        int gm = row0 + i;
        if (gm >= M) continue;
        if (EPI == 0) {
            #pragma unroll
            for (int j = 0; j < 4; j++)
                outb[(size_t)gm * N + col0 + j] = f2b(c[i][j] + bv[j]);
        } else if (EPI == 1) {
            int bw = gm / 196, n = gm % 196;
            int bb = bw / 25, wq = bw % 25;
            int wh = wq / 5, ww = wq % 5;
            int ii = n / 14, jj = n % 14;
            int r = wh * 14 + ii, cl = ww * 14 + jj;
            if (r < 64 && cl < 64) {
                size_t t = ((size_t)bb * 64 + r) * 64 + cl;
                #pragma unroll
                for (int j = 0; j < 4; j++)
                    outf[t * 768 + col0 + j] =
                        xres[t * 768 + col0 + j] + c[i][j] + bv[j];
            }
        } else if (EPI == 2) {
            #pragma unroll
            for (int j = 0; j < 4; j++) {
                float v = c[i][j] + bv[j];
                outb[(size_t)gm * N + col0 + j] =
                    f2b(0.5f * v * (1.0f + erff(v * 0.70710678118654752f)));
            }
        } else {
            #pragma unroll
            for (int j = 0; j < 4; j++)
                outf[(size_t)gm * N + col0 + j] =
                    yres[(size_t)gm * N + col0 + j] + c[i][j] + bv[j];
        }
    }
}

// ---------------------------------------------------------------------------
// K3: windowed attention, one block per (window, head). 4 waves, lockstep
// over 49 row-iterations (row n = it*4 + wave); uniform __syncthreads.
// logit(n,m) = 0.125*(q.k[m]) + q.Rh[i - m/14 + 13] + q.Rw[j - m%14 + 13]
// Softmax over all 196 keys (padded keys carry k=v=bias parts) == reference.
// qkv is bf16 (9800 x 2304), rel_pos_* fp32 (27 x 64).
// ---------------------------------------------------------------------------
__launch_bounds__(256)
__global__ void attn_kernel(const bf16* __restrict__ qkv,
                            const float* __restrict__ rel_h,
                            const float* __restrict__ rel_w,
                            bf16* __restrict__ attn_out)
{
    __shared__ bf16 k_lds[196 * 66];   // stride 66: 4B-aligned pairs
    __shared__ bf16 v_lds[196 * 64];
    __shared__ float relh[27 * 64];
    __shared__ float relw[27 * 64];
    __shared__ float qrow[4][64];
    __shared__ float biasH[4][16];
    __shared__ float biasW[4][16];
    __shared__ float prow[4][196];

    int bh = blockIdx.x;               // 0..599
    int bw = bh / 12, head = bh % 12;
    int tid = threadIdx.x, w = tid >> 6, lane = tid & 63;
    const size_t base = (size_t)bw * 196 * 2304 + head * 64;

    for (int idx = tid; idx < 196 * 64; idx += 256) {
        int m = idx >> 6, c = idx & 63;
        k_lds[m * 66 + c] = qkv[base + (size_t)m * 2304 + 768 + c];
        v_lds[m * 64 + c] = qkv[base + (size_t)m * 2304 + 1536 + c];
    }
    for (int idx = tid; idx < 27 * 64; idx += 256) {
        relh[idx] = rel_h[idx];
        relw[idx] = rel_w[idx];
    }
    __syncthreads();

    for (int it = 0; it < 49; it++) {
        int n = it * 4 + w;            // 0..195 exact
        int i = n / 14, j = n % 14;
        qrow[w][lane] = b2f(qkv[base + (size_t)n * 2304 + lane]);
        __syncthreads();

        if (lane < 28) {
            bool isH = lane < 14;
            int kk = isH ? lane : lane - 14;
            int ridx = (isH ? (i - kk) : (j - kk)) + 13;
            const float* R = (isH ? relh : relw) + ridx * 64;
            float acc = 0.f;
            #pragma unroll 8
            for (int c = 0; c < 64; c++) acc += qrow[w][c] * R[c];
            if (isH) biasH[w][kk] = acc; else biasW[w][kk] = acc;
        }
        __syncthreads();

        float l[4], el[4];
        float mx = -1e30f;
        #pragma unroll
        for (int ch = 0; ch < 4; ch++) {
            int m = ch * 64 + lane;
            if (m < 196) {
                float acc = 0.f;
                const bf16* krow = &k_lds[m * 66];
                #pragma unroll 8
                for (int c = 0; c < 64; c += 2) {
                    unsigned u = *(const unsigned*)&krow[c];
                    float2 q2 = *(const float2*)&qrow[w][c];
                    acc += q2.x * __uint_as_float(u << 16);
                    acc += q2.y * __uint_as_float(u & 0xffff0000u);
                }
                float lg = acc * 0.125f + biasH[w][m / 14] + biasW[w][m % 14];
                l[ch] = lg;
                mx = fmaxf(mx, lg);
            } else {
                l[ch] = -1e30f;
            }
        }
        #pragma unroll
        for (int o = 32; o > 0; o >>= 1) mx = fmaxf(mx, __shfl_xor(mx, o));
        float s = 0.f;
        #pragma unroll
        for (int ch = 0; ch < 4; ch++) {
            int m = ch * 64 + lane;
            if (m < 196) {
                el[ch] = expf(l[ch] - mx);
                s += el[ch];
                prow[w][m] = el[ch];
            }
        }
        #pragma unroll
        for (int o = 32; o > 0; o >>= 1) s += __shfl_xor(s, o);
        float inv = 1.0f / s;
        __syncthreads();

        float acc = 0.f;
        #pragma unroll 4
        for (int m = 0; m < 196; m++)
            acc += prow[w][m] * b2f(v_lds[m * 64 + lane]);
        attn_out[((size_t)bw * 196 + n) * 768 + head * 64 + lane] = f2b(acc * inv);
    }
}

// ---------------------------------------------------------------------------
// Workspace layout (bytes), peak ~117 MB (round-1 run wrote this range fine):
//   [0, 15.1M)    xw   (9800x768 bf16)   dead after qkv GEMM
//   [16M, 61.2M)  qkv  (9800x2304 bf16)  dead after attention
//   [62M, 77.1M)  att  (9800x768 bf16)   dead after proj
//   [78M, 103.2M) y    (8192x768 f32)    live until fc2
//   [104M,116.6M) xn2  (8192x768 bf16)
//   [0, 50.4M)    h    (8192x3072 bf16)  reuses xw+qkv region
// ---------------------------------------------------------------------------
extern "C" void kernel_launch(void* const* d_in, const int* in_sizes, int n_in,
                              void* d_out, int out_size, void* d_ws, size_t ws_size,
                              hipStream_t stream)
{
    const float* x      = (const float*)d_in[0];
    const float* n1w    = (const float*)d_in[1];
    const float* n1b    = (const float*)d_in[2];
    const float* qkv_w  = (const float*)d_in[3];
    const float* qkv_b  = (const float*)d_in[4];
    const float* proj_w = (const float*)d_in[5];
    const float* proj_b = (const float*)d_in[6];
    const float* rph    = (const float*)d_in[7];
    const float* rpw    = (const float*)d_in[8];
    const float* n2w    = (const float*)d_in[9];
    const float* n2b    = (const float*)d_in[10];
    const float* fc1_w  = (const float*)d_in[11];
    const float* fc1_b  = (const float*)d_in[12];
    const float* fc2_w  = (const float*)d_in[13];
    const float* fc2_b  = (const float*)d_in[14];
    float* out = (float*)d_out;

    char* ws = (char*)d_ws;
    bf16*  xw    = (bf16*)(ws);
    bf16*  qkvb  = (bf16*)(ws + ((size_t)16 << 20));
    bf16*  att   = (bf16*)(ws + ((size_t)62 << 20));
    float* y     = (float*)(ws + ((size_t)78 << 20));
    bf16*  xn2   = (bf16*)(ws + ((size_t)104 << 20));
    bf16*  h     = (bf16*)(ws);

    ln1_window_kernel<<<9800, 256, 0, stream>>>(x, n1w, n1b, xw);
    gemm_kernel<0><<<dim3(36, 154), 256, 0, stream>>>(
        xw, qkv_w, qkv_b, qkvb, nullptr, nullptr, nullptr, 9800, 2304, 768);
    attn_kernel<<<600, 256, 0, stream>>>(qkvb, rph, rpw, att);
    gemm_kernel<1><<<dim3(12, 154), 256, 0, stream>>>(
        att, proj_w, proj_b, nullptr, y, x, nullptr, 9800, 768, 768);
    ln2_kernel<<<8192, 256, 0, stream>>>(y, n2w, n2b, xn2);
    gemm_kernel<2><<<dim3(48, 128), 256, 0, stream>>>(
        xn2, fc1_w, fc1_b, h, nullptr, nullptr, nullptr, 8192, 3072, 768);
    gemm_kernel<3><<<dim3(12, 128), 256, 0, stream>>>(
        h, fc2_w, fc2_b, nullptr, out, nullptr, y, 8192, 768, 3072);
}

// Round 3
// 993.906 us; speedup vs baseline: 2.6112x; 2.6112x over previous
//
#include <hip/hip_runtime.h>
#include <hip/hip_bf16.h>
#include <math.h>

typedef __hip_bfloat16 bf16;
typedef __attribute__((ext_vector_type(8))) short short8;
typedef __attribute__((ext_vector_type(4))) float f32x4;

__device__ __forceinline__ float b2f(bf16 v) { return __bfloat162float(v); }
__device__ __forceinline__ bf16 f2b(float f) { return __float2bfloat16(f); }

// ---------------------------------------------------------------------------
// K0: weight transpose + fp32->bf16: W (K x N) -> Wt (N x K)
// ---------------------------------------------------------------------------
__launch_bounds__(256)
__global__ void transpose_w(const float* __restrict__ W, bf16* __restrict__ Wt,
                            int K, int N)
{
    __shared__ float t[32][33];
    int n0 = blockIdx.x * 32, k0 = blockIdx.y * 32;
    int tx = threadIdx.x, ty = threadIdx.y;      // 32 x 8
    #pragma unroll
    for (int i = 0; i < 4; i++)
        t[ty * 4 + i][tx] = W[(size_t)(k0 + ty * 4 + i) * N + n0 + tx];
    __syncthreads();
    #pragma unroll
    for (int i = 0; i < 4; i++)
        Wt[(size_t)(n0 + ty * 4 + i) * K + k0 + tx] = f2b(t[tx][ty * 4 + i]);
}

// ---------------------------------------------------------------------------
// K1: LayerNorm1 + window partition (zero pad) -> xw (9856 x 768) bf16
// ---------------------------------------------------------------------------
__launch_bounds__(256)
__global__ void ln1_window_kernel(const float* __restrict__ x,
                                  const float* __restrict__ wgt,
                                  const float* __restrict__ bia,
                                  bf16* __restrict__ xw)
{
    int blk = blockIdx.x;              // 0..9799
    int bw = blk / 196, n = blk % 196;
    int bb = bw / 25, wq = bw % 25;
    int wh = wq / 5, ww = wq % 5;
    int i = n / 14, j = n % 14;
    int r = wh * 14 + i, cl = ww * 14 + j;
    bf16* out = xw + (size_t)blk * 768;
    int tid = threadIdx.x;
    if (r >= 64 || cl >= 64) {
        #pragma unroll
        for (int t = 0; t < 3; t++) out[tid + t * 256] = f2b(0.0f);
        return;
    }
    const float* xin = x + (((size_t)bb * 64 + r) * 64 + cl) * 768;
    float v[3]; float s = 0.f, ss = 0.f;
    #pragma unroll
    for (int t = 0; t < 3; t++) {
        float f = xin[tid + t * 256];
        v[t] = f; s += f; ss += f * f;
    }
    #pragma unroll
    for (int o = 32; o > 0; o >>= 1) { s += __shfl_xor(s, o); ss += __shfl_xor(ss, o); }
    __shared__ float red[8];
    int w = tid >> 6, lane = tid & 63;
    if (lane == 0) { red[w] = s; red[4 + w] = ss; }
    __syncthreads();
    s  = red[0] + red[1] + red[2] + red[3];
    ss = red[4] + red[5] + red[6] + red[7];
    float mu = s * (1.0f / 768.0f);
    float var = ss * (1.0f / 768.0f) - mu * mu;
    float rs = rsqrtf(var + 1e-5f);
    #pragma unroll
    for (int t = 0; t < 3; t++) {
        int c = tid + t * 256;
        out[c] = f2b((v[t] - mu) * rs * wgt[c] + bia[c]);
    }
}

// ---------------------------------------------------------------------------
// K5: LayerNorm2 on y (f32, 8192 x 768) -> xn2 bf16
// ---------------------------------------------------------------------------
__launch_bounds__(256)
__global__ void ln2_kernel(const float* __restrict__ y,
                           const float* __restrict__ wgt,
                           const float* __restrict__ bia,
                           bf16* __restrict__ xn2)
{
    int blk = blockIdx.x;
    const float* yin = y + (size_t)blk * 768;
    bf16* out = xn2 + (size_t)blk * 768;
    int tid = threadIdx.x;
    float v[3]; float s = 0.f, ss = 0.f;
    #pragma unroll
    for (int t = 0; t < 3; t++) {
        float f = yin[tid + t * 256];
        v[t] = f; s += f; ss += f * f;
    }
    #pragma unroll
    for (int o = 32; o > 0; o >>= 1) { s += __shfl_xor(s, o); ss += __shfl_xor(ss, o); }
    __shared__ float red[8];
    int w = tid >> 6, lane = tid & 63;
    if (lane == 0) { red[w] = s; red[4 + w] = ss; }
    __syncthreads();
    s  = red[0] + red[1] + red[2] + red[3];
    ss = red[4] + red[5] + red[6] + red[7];
    float mu = s * (1.0f / 768.0f);
    float var = ss * (1.0f / 768.0f) - mu * mu;
    float rs = rsqrtf(var + 1e-5f);
    #pragma unroll
    for (int t = 0; t < 3; t++) {
        int c = tid + t * 256;
        out[c] = f2b((v[t] - mu) * rs * wgt[c] + bia[c]);
    }
}

// ---------------------------------------------------------------------------
// MFMA GEMM (m97 structure): C = A(M x K) @ Bt^T + bias.
// A bf16 row-major (M rows padded to tile), Bt bf16 (N x K) row-major.
// 128x128 tile, BK=32, 4 waves, 16x16x32 bf16 MFMA, global_load_lds width 16.
// C/D layout: col = lane&15, row = (lane>>4)*4 + reg   [guide m89/m91]
//  EPI 0: store bf16                         (qkv)
//  EPI 1: window-unpartition+crop, y = x + C (proj, f32 out)
//  EPI 2: exact GELU, store bf16             (fc1)
//  EPI 3: outf = yres + C, f32               (fc2 -> d_out)
// ---------------------------------------------------------------------------
template<int EPI>
__launch_bounds__(256)
__global__ void mfma_gemm(const bf16* __restrict__ A,
                          const bf16* __restrict__ Bt,
                          const float* __restrict__ bias,
                          bf16* __restrict__ outb,
                          float* __restrict__ outf,
                          const float* __restrict__ xres,
                          const float* __restrict__ yres,
                          int M, int N, int K)
{
    __shared__ bf16 As[128 * 32];
    __shared__ bf16 Bs[128 * 32];
    const int tid = threadIdx.x;
    const int w = tid >> 6, lane = tid & 63;
    const int wm = (w & 1) * 64, wn = (w >> 1) * 64;
    const int tm = blockIdx.y * 128, tn = blockIdx.x * 128;

    f32x4 acc[4][4] = {};

    for (int k0 = 0; k0 < K; k0 += 32) {
        #pragma unroll
        for (int i = 0; i < 2; i++) {
            int e = i * 256 + tid;
            int r = e >> 2, ch = e & 3;
            __builtin_amdgcn_global_load_lds(
                (const __attribute__((address_space(1))) unsigned*)(A + (size_t)(tm + r) * K + k0 + ch * 8),
                (__attribute__((address_space(3))) unsigned*)(As + e * 8),
                16, 0, 0);
            __builtin_amdgcn_global_load_lds(
                (const __attribute__((address_space(1))) unsigned*)(Bt + (size_t)(tn + r) * K + k0 + ch * 8),
                (__attribute__((address_space(3))) unsigned*)(Bs + e * 8),
                16, 0, 0);
        }
        __syncthreads();
        short8 af[4], bfr[4];
        #pragma unroll
        for (int mi = 0; mi < 4; mi++)
            af[mi] = *(const short8*)(As + (wm + mi * 16 + (lane & 15)) * 32 + (lane >> 4) * 8);
        #pragma unroll
        for (int ni = 0; ni < 4; ni++)
            bfr[ni] = *(const short8*)(Bs + (wn + ni * 16 + (lane & 15)) * 32 + (lane >> 4) * 8);
        #pragma unroll
        for (int mi = 0; mi < 4; mi++)
            #pragma unroll
            for (int ni = 0; ni < 4; ni++)
                acc[mi][ni] = __builtin_amdgcn_mfma_f32_16x16x32_bf16(
                    af[mi], bfr[ni], acc[mi][ni], 0, 0, 0);
        __syncthreads();
    }

    const int col_l = lane & 15, row_l = (lane >> 4) * 4;
    float bv[4];
    #pragma unroll
    for (int ni = 0; ni < 4; ni++) bv[ni] = bias[tn + wn + ni * 16 + col_l];

    #pragma unroll
    for (int mi = 0; mi < 4; mi++) {
        #pragma unroll
        for (int r = 0; r < 4; r++) {
            int gm = tm + wm + mi * 16 + row_l + r;
            if (gm >= M) continue;
            if (EPI == 1) {
                int bw = gm / 196, n = gm % 196;
                int bb = bw / 25, wq = bw % 25;
                int wh = wq / 5, ww = wq % 5;
                int ii = n / 14, jj = n % 14;
                int rr = wh * 14 + ii, cl = ww * 14 + jj;
                if (rr >= 64 || cl >= 64) continue;
                size_t t = ((size_t)bb * 64 + rr) * 64 + cl;
                #pragma unroll
                for (int ni = 0; ni < 4; ni++) {
                    int gn = tn + wn + ni * 16 + col_l;
                    outf[t * 768 + gn] = xres[t * 768 + gn] + acc[mi][ni][r] + bv[ni];
                }
            } else {
                #pragma unroll
                for (int ni = 0; ni < 4; ni++) {
                    int gn = tn + wn + ni * 16 + col_l;
                    float v = acc[mi][ni][r] + bv[ni];
                    if (EPI == 0) {
                        outb[(size_t)gm * N + gn] = f2b(v);
                    } else if (EPI == 2) {
                        outb[(size_t)gm * N + gn] =
                            f2b(0.5f * v * (1.0f + erff(v * 0.70710678118654752f)));
                    } else {
                        outf[(size_t)gm * N + gn] = yres[(size_t)gm * N + gn] + v;
                    }
                }
            }
        }
    }
}

// ---------------------------------------------------------------------------
// K3: windowed attention v2. One block per (window, head), 4 independent
// waves, each handling 49 query rows with wave-synchronous LDS (no barriers
// in the loop). rel rows padded to 68 floats (no stride-64 bank collision);
// V pair-interleaved so PV reads are b32.
// ---------------------------------------------------------------------------
__launch_bounds__(256)
__global__ void attn_kernel(const bf16* __restrict__ qkv,
                            const float* __restrict__ rel_h,
                            const float* __restrict__ rel_w,
                            bf16* __restrict__ att)
{
    __shared__ bf16 k_lds[196 * 66];      // row stride 66 -> bank m + c/2 (2-way, free)
    __shared__ bf16 v_il[98 * 128];       // v_il[(m>>1)*128 + d*2 + (m&1)]
    __shared__ float relh[27][68];
    __shared__ float relw[27][68];
    __shared__ float qs[4][64];
    __shared__ float bH[4][14];
    __shared__ float bW[4][14];
    __shared__ float pr[4][196];

    int bh = blockIdx.x;                  // 0..599
    int bwi = bh / 12, head = bh % 12;
    int tid = threadIdx.x, w = tid >> 6, lane = tid & 63;
    const size_t base = (size_t)bwi * 196 * 2304 + head * 64;

    for (int idx = tid; idx < 196 * 32; idx += 256) {
        int m = idx >> 5, c2 = idx & 31;  // covers cols 2*c2, 2*c2+1
        unsigned ku = *(const unsigned*)(qkv + base + (size_t)m * 2304 + 768 + 2 * c2);
        *(unsigned*)(k_lds + m * 66 + 2 * c2) = ku;
        unsigned vu = *(const unsigned*)(qkv + base + (size_t)m * 2304 + 1536 + 2 * c2);
        bf16* vp = v_il + (m >> 1) * 128 + (m & 1);
        vp[(2 * c2) * 2]     = ((const bf16*)&vu)[0];
        vp[(2 * c2 + 1) * 2] = ((const bf16*)&vu)[1];
    }
    for (int idx = tid; idx < 27 * 64; idx += 256) {
        relh[idx >> 6][idx & 63] = rel_h[idx];
        relw[idx >> 6][idx & 63] = rel_w[idx];
    }
    __syncthreads();

    for (int it = 0; it < 49; it++) {
        int n = w * 49 + it;              // this wave's query row
        int i = n / 14, j = n % 14;
        qs[w][lane] = b2f(qkv[base + (size_t)n * 2304 + lane]);
        __builtin_amdgcn_wave_barrier();

        if (lane < 28) {
            bool isH = lane < 14;
            int kk = isH ? lane : lane - 14;
            int ridx = (isH ? (i - kk) : (j - kk)) + 13;
            const float* R = isH ? relh[ridx] : relw[ridx];
            float acc = 0.f;
            #pragma unroll
            for (int c = 0; c < 64; c += 4) {
                float4 q4 = *(const float4*)&qs[w][c];
                float4 r4 = *(const float4*)&R[c];
                acc += q4.x * r4.x + q4.y * r4.y + q4.z * r4.z + q4.w * r4.w;
            }
            if (isH) bH[w][kk] = acc; else bW[w][kk] = acc;
        }
        __builtin_amdgcn_wave_barrier();

        float l[4];
        float mx = -1e30f;
        #pragma unroll
        for (int ch = 0; ch < 4; ch++) {
            int m = ch * 64 + lane;
            if (m < 196) {
                float acc = 0.f;
                const bf16* krow = k_lds + m * 66;
                #pragma unroll 8
                for (int c = 0; c < 64; c += 2) {
                    unsigned u = *(const unsigned*)(krow + c);
                    float2 q2 = *(const float2*)&qs[w][c];
                    acc += q2.x * __uint_as_float(u << 16);
                    acc += q2.y * __uint_as_float(u & 0xffff0000u);
                }
                float lg = acc * 0.125f + bH[w][m / 14] + bW[w][m % 14];
                l[ch] = lg; mx = fmaxf(mx, lg);
            } else l[ch] = -1e30f;
        }
        #pragma unroll
        for (int o = 32; o > 0; o >>= 1) mx = fmaxf(mx, __shfl_xor(mx, o));
        float s = 0.f;
        #pragma unroll
        for (int ch = 0; ch < 4; ch++) {
            int m = ch * 64 + lane;
            if (m < 196) {
                float e = __expf(l[ch] - mx);
                pr[w][m] = e; s += e;
            }
        }
        #pragma unroll
        for (int o = 32; o > 0; o >>= 1) s += __shfl_xor(s, o);
        float inv = 1.0f / s;
        __builtin_amdgcn_wave_barrier();

        float acc = 0.f;
        #pragma unroll 2
        for (int m2 = 0; m2 < 98; m2++) {
            unsigned u = *(const unsigned*)(v_il + m2 * 128 + 2 * lane);
            float2 p2 = *(const float2*)&pr[w][2 * m2];
            acc += p2.x * __uint_as_float(u << 16);
            acc += p2.y * __uint_as_float(u & 0xffff0000u);
        }
        att[((size_t)bwi * 196 + n) * 768 + head * 64 + lane] = f2b(acc * inv);
    }
}

// ---------------------------------------------------------------------------
// Workspace (MiB offsets, peak 113 MiB; round-2 proved >=117 usable):
//   [0,    3.5)  qkv_wt 2304x768 bf16
//   [3.5,  5)    proj_wt 768x768
//   [5,    9.5)  fc1_wt 3072x768
//   [10,  14.5)  fc2_wt 768x3072
//   [15,  29.5)  xw 9856x768 bf16      (dead after qkv GEMM; xn2 reuses)
//   [30,  73.4)  qkv 9856x2304 bf16    (dead after attn; h reuses)
//   [74,  88.5)  att 9856x768 bf16     (dead after proj; h reuses)
//   [89, 113)    y 8192x768 f32        (live to fc2)
//   [15,  27.1)  xn2 8192x768 bf16
//   [30,  78)    h 8192x3072 bf16
// ---------------------------------------------------------------------------
extern "C" void kernel_launch(void* const* d_in, const int* in_sizes, int n_in,
                              void* d_out, int out_size, void* d_ws, size_t ws_size,
                              hipStream_t stream)
{
    const float* x      = (const float*)d_in[0];
    const float* n1w    = (const float*)d_in[1];
    const float* n1b    = (const float*)d_in[2];
    const float* qkv_w  = (const float*)d_in[3];
    const float* qkv_b  = (const float*)d_in[4];
    const float* proj_w = (const float*)d_in[5];
    const float* proj_b = (const float*)d_in[6];
    const float* rph    = (const float*)d_in[7];
    const float* rpw    = (const float*)d_in[8];
    const float* n2w    = (const float*)d_in[9];
    const float* n2b    = (const float*)d_in[10];
    const float* fc1_w  = (const float*)d_in[11];
    const float* fc1_b  = (const float*)d_in[12];
    const float* fc2_w  = (const float*)d_in[13];
    const float* fc2_b  = (const float*)d_in[14];
    float* out = (float*)d_out;

    char* ws = (char*)d_ws;
    const size_t MB = (size_t)1 << 20;
    bf16* qkv_wt  = (bf16*)(ws);
    bf16* proj_wt = (bf16*)(ws + (size_t)(3.5 * MB));
    bf16* fc1_wt  = (bf16*)(ws + 5 * MB);
    bf16* fc2_wt  = (bf16*)(ws + 10 * MB);
    bf16* xw      = (bf16*)(ws + 15 * MB);
    bf16* qkvb    = (bf16*)(ws + 30 * MB);
    bf16* att     = (bf16*)(ws + 74 * MB);
    float* y      = (float*)(ws + 89 * MB);
    bf16* xn2     = (bf16*)(ws + 15 * MB);
    bf16* h       = (bf16*)(ws + 30 * MB);

    // 0) weight transposes (fp32 -> bf16, (K,N) -> (N,K))
    transpose_w<<<dim3(72, 24), dim3(32, 8), 0, stream>>>(qkv_w,  qkv_wt,  768, 2304);
    transpose_w<<<dim3(24, 24), dim3(32, 8), 0, stream>>>(proj_w, proj_wt, 768, 768);
    transpose_w<<<dim3(96, 24), dim3(32, 8), 0, stream>>>(fc1_w,  fc1_wt,  768, 3072);
    transpose_w<<<dim3(24, 96), dim3(32, 8), 0, stream>>>(fc2_w,  fc2_wt,  3072, 768);

    // 1) LN1 + window partition
    ln1_window_kernel<<<9800, 256, 0, stream>>>(x, n1w, n1b, xw);
    // 2) qkv = xw @ qkv_w + b   (9800 x 2304, Mtiles=77)
    mfma_gemm<0><<<dim3(18, 77), 256, 0, stream>>>(
        xw, qkv_wt, qkv_b, qkvb, nullptr, nullptr, nullptr, 9800, 2304, 768);
    // 3) attention
    attn_kernel<<<600, 256, 0, stream>>>(qkvb, rph, rpw, att);
    // 4) proj + unpartition + residual -> y
    mfma_gemm<1><<<dim3(6, 77), 256, 0, stream>>>(
        att, proj_wt, proj_b, nullptr, y, x, nullptr, 9800, 768, 768);
    // 5) LN2
    ln2_kernel<<<8192, 256, 0, stream>>>(y, n2w, n2b, xn2);
    // 6) h = gelu(xn2 @ fc1_w + b)
    mfma_gemm<2><<<dim3(24, 64), 256, 0, stream>>>(
        xn2, fc1_wt, fc1_b, h, nullptr, nullptr, nullptr, 8192, 3072, 768);
    // 7) out = y + h @ fc2_w + b
    mfma_gemm<3><<<dim3(6, 64), 256, 0, stream>>>(
        h, fc2_wt, fc2_b, nullptr, out, nullptr, y, 8192, 768, 3072);
}

// Round 4
// 484.950 us; speedup vs baseline: 5.3516x; 2.0495x over previous
//
#include <hip/hip_runtime.h>
#include <hip/hip_bf16.h>
#include <math.h>

typedef __hip_bfloat16 bf16;
typedef __attribute__((ext_vector_type(8))) short short8;
typedef __attribute__((ext_vector_type(4))) float f32x4;

__device__ __forceinline__ float b2f(bf16 v) { return __bfloat162float(v); }
__device__ __forceinline__ bf16 f2b(float f) { return __float2bfloat16(f); }

// ---------------------------------------------------------------------------
// K0: weight transpose + fp32->bf16: W (K x N) -> Wt (N x K)
// ---------------------------------------------------------------------------
__launch_bounds__(256)
__global__ void transpose_w(const float* __restrict__ W, bf16* __restrict__ Wt,
                            int K, int N)
{
    __shared__ float t[32][33];
    int n0 = blockIdx.x * 32, k0 = blockIdx.y * 32;
    int tx = threadIdx.x, ty = threadIdx.y;      // 32 x 8
    #pragma unroll
    for (int i = 0; i < 4; i++)
        t[ty * 4 + i][tx] = W[(size_t)(k0 + ty * 4 + i) * N + n0 + tx];
    __syncthreads();
    #pragma unroll
    for (int i = 0; i < 4; i++)
        Wt[(size_t)(n0 + ty * 4 + i) * K + k0 + tx] = f2b(t[tx][ty * 4 + i]);
}

// ---------------------------------------------------------------------------
// K1: LayerNorm1 + window partition (zero pad) -> xw (9856 x 768) bf16
// ---------------------------------------------------------------------------
__launch_bounds__(256)
__global__ void ln1_window_kernel(const float* __restrict__ x,
                                  const float* __restrict__ wgt,
                                  const float* __restrict__ bia,
                                  bf16* __restrict__ xw)
{
    int blk = blockIdx.x;              // 0..9799
    int bw = blk / 196, n = blk % 196;
    int bb = bw / 25, wq = bw % 25;
    int wh = wq / 5, ww = wq % 5;
    int i = n / 14, j = n % 14;
    int r = wh * 14 + i, cl = ww * 14 + j;
    bf16* out = xw + (size_t)blk * 768;
    int tid = threadIdx.x;
    if (r >= 64 || cl >= 64) {
        #pragma unroll
        for (int t = 0; t < 3; t++) out[tid + t * 256] = f2b(0.0f);
        return;
    }
    const float* xin = x + (((size_t)bb * 64 + r) * 64 + cl) * 768;
    float v[3]; float s = 0.f, ss = 0.f;
    #pragma unroll
    for (int t = 0; t < 3; t++) {
        float f = xin[tid + t * 256];
        v[t] = f; s += f; ss += f * f;
    }
    #pragma unroll
    for (int o = 32; o > 0; o >>= 1) { s += __shfl_xor(s, o); ss += __shfl_xor(ss, o); }
    __shared__ float red[8];
    int w = tid >> 6, lane = tid & 63;
    if (lane == 0) { red[w] = s; red[4 + w] = ss; }
    __syncthreads();
    s  = red[0] + red[1] + red[2] + red[3];
    ss = red[4] + red[5] + red[6] + red[7];
    float mu = s * (1.0f / 768.0f);
    float var = ss * (1.0f / 768.0f) - mu * mu;
    float rs = rsqrtf(var + 1e-5f);
    #pragma unroll
    for (int t = 0; t < 3; t++) {
        int c = tid + t * 256;
        out[c] = f2b((v[t] - mu) * rs * wgt[c] + bia[c]);
    }
}

// ---------------------------------------------------------------------------
// K5: LayerNorm2 on y (f32, 8192 x 768) -> xn2 bf16
// ---------------------------------------------------------------------------
__launch_bounds__(256)
__global__ void ln2_kernel(const float* __restrict__ y,
                           const float* __restrict__ wgt,
                           const float* __restrict__ bia,
                           bf16* __restrict__ xn2)
{
    int blk = blockIdx.x;
    const float* yin = y + (size_t)blk * 768;
    bf16* out = xn2 + (size_t)blk * 768;
    int tid = threadIdx.x;
    float v[3]; float s = 0.f, ss = 0.f;
    #pragma unroll
    for (int t = 0; t < 3; t++) {
        float f = yin[tid + t * 256];
        v[t] = f; s += f; ss += f * f;
    }
    #pragma unroll
    for (int o = 32; o > 0; o >>= 1) { s += __shfl_xor(s, o); ss += __shfl_xor(ss, o); }
    __shared__ float red[8];
    int w = tid >> 6, lane = tid & 63;
    if (lane == 0) { red[w] = s; red[4 + w] = ss; }
    __syncthreads();
    s  = red[0] + red[1] + red[2] + red[3];
    ss = red[4] + red[5] + red[6] + red[7];
    float mu = s * (1.0f / 768.0f);
    float var = ss * (1.0f / 768.0f) - mu * mu;
    float rs = rsqrtf(var + 1e-5f);
    #pragma unroll
    for (int t = 0; t < 3; t++) {
        int c = tid + t * 256;
        out[c] = f2b((v[t] - mu) * rs * wgt[c] + bia[c]);
    }
}

// ---------------------------------------------------------------------------
// MFMA GEMM (m97 structure): C = A(M x K) @ Bt^T + bias.  (unchanged, verified)
// ---------------------------------------------------------------------------
template<int EPI>
__launch_bounds__(256)
__global__ void mfma_gemm(const bf16* __restrict__ A,
                          const bf16* __restrict__ Bt,
                          const float* __restrict__ bias,
                          bf16* __restrict__ outb,
                          float* __restrict__ outf,
                          const float* __restrict__ xres,
                          const float* __restrict__ yres,
                          int M, int N, int K)
{
    __shared__ bf16 As[128 * 32];
    __shared__ bf16 Bs[128 * 32];
    const int tid = threadIdx.x;
    const int w = tid >> 6, lane = tid & 63;
    const int wm = (w & 1) * 64, wn = (w >> 1) * 64;
    const int tm = blockIdx.y * 128, tn = blockIdx.x * 128;

    f32x4 acc[4][4] = {};

    for (int k0 = 0; k0 < K; k0 += 32) {
        #pragma unroll
        for (int i = 0; i < 2; i++) {
            int e = i * 256 + tid;
            int r = e >> 2, ch = e & 3;
            __builtin_amdgcn_global_load_lds(
                (const __attribute__((address_space(1))) unsigned*)(A + (size_t)(tm + r) * K + k0 + ch * 8),
                (__attribute__((address_space(3))) unsigned*)(As + e * 8),
                16, 0, 0);
            __builtin_amdgcn_global_load_lds(
                (const __attribute__((address_space(1))) unsigned*)(Bt + (size_t)(tn + r) * K + k0 + ch * 8),
                (__attribute__((address_space(3))) unsigned*)(Bs + e * 8),
                16, 0, 0);
        }
        __syncthreads();
        short8 af[4], bfr[4];
        #pragma unroll
        for (int mi = 0; mi < 4; mi++)
            af[mi] = *(const short8*)(As + (wm + mi * 16 + (lane & 15)) * 32 + (lane >> 4) * 8);
        #pragma unroll
        for (int ni = 0; ni < 4; ni++)
            bfr[ni] = *(const short8*)(Bs + (wn + ni * 16 + (lane & 15)) * 32 + (lane >> 4) * 8);
        #pragma unroll
        for (int mi = 0; mi < 4; mi++)
            #pragma unroll
            for (int ni = 0; ni < 4; ni++)
                acc[mi][ni] = __builtin_amdgcn_mfma_f32_16x16x32_bf16(
                    af[mi], bfr[ni], acc[mi][ni], 0, 0, 0);
        __syncthreads();
    }

    const int col_l = lane & 15, row_l = (lane >> 4) * 4;
    float bv[4];
    #pragma unroll
    for (int ni = 0; ni < 4; ni++) bv[ni] = bias[tn + wn + ni * 16 + col_l];

    #pragma unroll
    for (int mi = 0; mi < 4; mi++) {
        #pragma unroll
        for (int r = 0; r < 4; r++) {
            int gm = tm + wm + mi * 16 + row_l + r;
            if (gm >= M) continue;
            if (EPI == 1) {
                int bw = gm / 196, n = gm % 196;
                int bb = bw / 25, wq = bw % 25;
                int wh = wq / 5, ww = wq % 5;
                int ii = n / 14, jj = n % 14;
                int rr = wh * 14 + ii, cl = ww * 14 + jj;
                if (rr >= 64 || cl >= 64) continue;
                size_t t = ((size_t)bb * 64 + rr) * 64 + cl;
                #pragma unroll
                for (int ni = 0; ni < 4; ni++) {
                    int gn = tn + wn + ni * 16 + col_l;
                    outf[t * 768 + gn] = xres[t * 768 + gn] + acc[mi][ni][r] + bv[ni];
                }
            } else {
                #pragma unroll
                for (int ni = 0; ni < 4; ni++) {
                    int gn = tn + wn + ni * 16 + col_l;
                    float v = acc[mi][ni][r] + bv[ni];
                    if (EPI == 0) {
                        outb[(size_t)gm * N + gn] = f2b(v);
                    } else if (EPI == 2) {
                        outb[(size_t)gm * N + gn] =
                            f2b(0.5f * v * (1.0f + erff(v * 0.70710678118654752f)));
                    } else {
                        outf[(size_t)gm * N + gn] = yres[(size_t)gm * N + gn] + v;
                    }
                }
            }
        }
    }
}

// ---------------------------------------------------------------------------
// K3: fused MFMA windowed attention. One block per (window, head), 4 waves.
// B matrix (272 x 64) = [K rows 0..207 (196 real) | Rh table 208..239 (27 real)
//                        | Rw table 240..271 (27 real)], stored as two BK=32
// halves (GEMM-proven LDS pattern). One QK pass gives scores AND q.relTable.
// Scores C-layout: col = lane&15, row = (lane>>4)*4+reg.
// P round-trips LDS (bf16, pre-scaled 1/sum, zero-padded); V transposed in
// LDS as PV B-operand (d x key).
// ---------------------------------------------------------------------------
__launch_bounds__(256)
__global__ void attn_kernel(const bf16* __restrict__ qkv,
                            const float* __restrict__ rel_h,
                            const float* __restrict__ rel_w,
                            bf16* __restrict__ att)
{
    __shared__ bf16 BsLo[272 * 32];     // k 0..31
    __shared__ bf16 BsHi[272 * 32];     // k 32..63
    __shared__ bf16 Vt[64 * 224];       // Vt[d*224 + key], keys 196..223 zero
    __shared__ bf16 Ps[4][16 * 232];    // per-wave P, row stride 232 (16B-aligned)
    __shared__ float relS[4][2][16][32]; // per-wave q.relTable [h/w][row][tblidx]

    int bh = blockIdx.x;                // 0..599
    int bwi = bh / 12, head = bh % 12;
    int tid = threadIdx.x, w = tid >> 6, lane = tid & 63;
    const size_t base = (size_t)bwi * 196 * 2304 + head * 64;

    // --- stage: zero pad rows 196..271 of B
    for (int idx = tid; idx < 76 * 16; idx += 256) {
        int r = 196 + (idx >> 4), cd = idx & 15;
        ((unsigned*)BsLo)[r * 16 + cd] = 0u;
        ((unsigned*)BsHi)[r * 16 + cd] = 0u;
    }
    // K rows 0..195
    for (int idx = tid; idx < 196 * 32; idx += 256) {
        int m = idx >> 5, c2 = idx & 31;
        unsigned u = *(const unsigned*)(qkv + base + (size_t)m * 2304 + 768 + 2 * c2);
        if (c2 < 16) ((unsigned*)BsLo)[m * 16 + c2] = u;
        else         ((unsigned*)BsHi)[m * 16 + (c2 - 16)] = u;
    }
    // rel tables fp32 -> bf16 into rows 208.. / 240..
    for (int idx = tid; idx < 27 * 32; idx += 256) {
        int t = idx >> 5, c2 = idx & 31;
        float2 h2 = *(const float2*)(rel_h + t * 64 + 2 * c2);
        float2 w2 = *(const float2*)(rel_w + t * 64 + 2 * c2);
        bf16 hb[2] = { f2b(h2.x), f2b(h2.y) };
        bf16 wb[2] = { f2b(w2.x), f2b(w2.y) };
        int r1 = 208 + t, r2 = 240 + t;
        if (c2 < 16) {
            ((unsigned*)BsLo)[r1 * 16 + c2] = *(unsigned*)hb;
            ((unsigned*)BsLo)[r2 * 16 + c2] = *(unsigned*)wb;
        } else {
            ((unsigned*)BsHi)[r1 * 16 + c2 - 16] = *(unsigned*)hb;
            ((unsigned*)BsHi)[r2 * 16 + c2 - 16] = *(unsigned*)wb;
        }
    }
    // Vt zero pad cols 196..223 (avoid NaN*0 in PV)
    for (int idx = tid; idx < 64 * 14; idx += 256) {
        int d = idx / 14, cd = idx % 14;
        ((unsigned*)Vt)[d * 112 + 98 + cd] = 0u;
    }
    // V transpose: thread handles (d, keypair) -> 1 dword LDS write (conflict-free)
    for (int idx = tid; idx < 64 * 98; idx += 256) {
        int d = idx / 98, kp = idx % 98;
        bf16 v0 = qkv[base + (size_t)(2 * kp) * 2304 + 1536 + d];
        bf16 v1 = qkv[base + (size_t)(2 * kp + 1) * 2304 + 1536 + d];
        bf16 pk[2] = { v0, v1 };
        ((unsigned*)Vt)[d * 112 + kp] = *(unsigned*)pk;
    }
    // Ps zero pad cols 208..231 (own wave)
    for (int t = lane; t < 16 * 12; t += 64) {
        int r = t / 12, cd = t % 12;
        ((unsigned*)&Ps[w][0])[r * 116 + 104 + cd] = 0u;
    }
    __syncthreads();

    const int cl = lane & 15, rg = lane >> 4;
    const int lr0 = rg * 4;

    for (int mt = w; mt < 13; mt += 4) {
        // Q A-frags straight from global (row q0, contiguous k)
        int q0 = mt * 16 + cl;
        const bf16* qp = qkv + base + (size_t)q0 * 2304 + rg * 8;
        short8 af0 = *(const short8*)(qp);
        short8 af1 = *(const short8*)(qp + 32);

        // QK + rel scores: 17 n-tiles
        f32x4 sc[17];
        #pragma unroll
        for (int ni = 0; ni < 17; ni++) {
            short8 blo = *(const short8*)(BsLo + (ni * 16 + cl) * 32 + rg * 8);
            short8 bhi = *(const short8*)(BsHi + (ni * 16 + cl) * 32 + rg * 8);
            f32x4 t = {};
            t = __builtin_amdgcn_mfma_f32_16x16x32_bf16(af0, blo, t, 0, 0, 0);
            sc[ni] = __builtin_amdgcn_mfma_f32_16x16x32_bf16(af1, bhi, t, 0, 0, 0);
        }
        // rel tiles -> LDS (cross-lane diagonal gather needs round-trip)
        #pragma unroll
        for (int t = 0; t < 2; t++)
            #pragma unroll
            for (int r = 0; r < 4; r++) {
                relS[w][0][lr0 + r][t * 16 + cl] = sc[13 + t][r];
                relS[w][1][lr0 + r][t * 16 + cl] = sc[15 + t][r];
            }
        __builtin_amdgcn_wave_barrier();

        // softmax (rows lr0..lr0+3, cols = cl + 16*ni)
        int iq[4], jq[4];
        #pragma unroll
        for (int r = 0; r < 4; r++) { int q = mt * 16 + lr0 + r; iq[r] = q / 14; jq[r] = q % 14; }
        float mx[4] = { -1e30f, -1e30f, -1e30f, -1e30f };
        #pragma unroll
        for (int ni = 0; ni < 13; ni++) {
            int c = ni * 16 + cl;
            int kh = c / 14; if (kh > 13) kh = 13;
            int kw = c - (c / 14) * 14;
            bool valid = c < 196;
            #pragma unroll
            for (int r = 0; r < 4; r++) {
                float lg = sc[ni][r] * 0.125f
                         + relS[w][0][lr0 + r][iq[r] - kh + 13]
                         + relS[w][1][lr0 + r][jq[r] - kw + 13];
                sc[ni][r] = valid ? lg : -1e30f;
                mx[r] = fmaxf(mx[r], sc[ni][r]);
            }
        }
        float sum[4];
        #pragma unroll
        for (int r = 0; r < 4; r++) {
            #pragma unroll
            for (int o = 1; o < 16; o <<= 1) mx[r] = fmaxf(mx[r], __shfl_xor(mx[r], o));
            sum[r] = 0.f;
        }
        #pragma unroll
        for (int ni = 0; ni < 13; ni++)
            #pragma unroll
            for (int r = 0; r < 4; r++) {
                float e = __expf(sc[ni][r] - mx[r]);
                sc[ni][r] = e; sum[r] += e;
            }
        #pragma unroll
        for (int r = 0; r < 4; r++) {
            #pragma unroll
            for (int o = 1; o < 16; o <<= 1) sum[r] += __shfl_xor(sum[r], o);
            sum[r] = 1.0f / sum[r];
        }
        // P (pre-scaled) -> LDS bf16
        #pragma unroll
        for (int ni = 0; ni < 13; ni++)
            #pragma unroll
            for (int r = 0; r < 4; r++)
                Ps[w][(lr0 + r) * 232 + ni * 16 + cl] = f2b(sc[ni][r] * sum[r]);
        __builtin_amdgcn_wave_barrier();

        // PV: out(16 x 64) = P(16 x 224) @ V(224 x 64)
        f32x4 ov[4] = {};
        #pragma unroll
        for (int ks = 0; ks < 7; ks++) {
            short8 pa = *(const short8*)(&Ps[w][cl * 232 + ks * 32 + rg * 8]);
            #pragma unroll
            for (int ni = 0; ni < 4; ni++) {
                short8 vb = *(const short8*)(Vt + (ni * 16 + cl) * 224 + ks * 32 + rg * 8);
                ov[ni] = __builtin_amdgcn_mfma_f32_16x16x32_bf16(pa, vb, ov[ni], 0, 0, 0);
            }
        }
        // store (skip padded q rows)
        #pragma unroll
        for (int r = 0; r < 4; r++) {
            int q = mt * 16 + lr0 + r;
            if (q < 196) {
                size_t ob = ((size_t)bwi * 196 + q) * 768 + head * 64;
                #pragma unroll
                for (int ni = 0; ni < 4; ni++)
                    att[ob + ni * 16 + cl] = f2b(ov[ni][r]);
            }
        }
    }
}

// ---------------------------------------------------------------------------
// Workspace (MiB offsets, peak 113 MiB):
//   [0,3.5) qkv_wt | [3.5,5) proj_wt | [5,9.5) fc1_wt | [10,14.5) fc2_wt
//   [15,29.5) xw 9856x768 bf16 (xn2 reuses) | [30,73.4) qkv 9856x2304 (h reuses)
//   [74,88.5) att 9856x768 | [89,113) y 8192x768 f32
// ---------------------------------------------------------------------------
extern "C" void kernel_launch(void* const* d_in, const int* in_sizes, int n_in,
                              void* d_out, int out_size, void* d_ws, size_t ws_size,
                              hipStream_t stream)
{
    const float* x      = (const float*)d_in[0];
    const float* n1w    = (const float*)d_in[1];
    const float* n1b    = (const float*)d_in[2];
    const float* qkv_w  = (const float*)d_in[3];
    const float* qkv_b  = (const float*)d_in[4];
    const float* proj_w = (const float*)d_in[5];
    const float* proj_b = (const float*)d_in[6];
    const float* rph    = (const float*)d_in[7];
    const float* rpw    = (const float*)d_in[8];
    const float* n2w    = (const float*)d_in[9];
    const float* n2b    = (const float*)d_in[10];
    const float* fc1_w  = (const float*)d_in[11];
    const float* fc1_b  = (const float*)d_in[12];
    const float* fc2_w  = (const float*)d_in[13];
    const float* fc2_b  = (const float*)d_in[14];
    float* out = (float*)d_out;

    char* ws = (char*)d_ws;
    const size_t MB = (size_t)1 << 20;
    bf16* qkv_wt  = (bf16*)(ws);
    bf16* proj_wt = (bf16*)(ws + (size_t)(3.5 * MB));
    bf16* fc1_wt  = (bf16*)(ws + 5 * MB);
    bf16* fc2_wt  = (bf16*)(ws + 10 * MB);
    bf16* xw      = (bf16*)(ws + 15 * MB);
    bf16* qkvb    = (bf16*)(ws + 30 * MB);
    bf16* att     = (bf16*)(ws + 74 * MB);
    float* y      = (float*)(ws + 89 * MB);
    bf16* xn2     = (bf16*)(ws + 15 * MB);
    bf16* h       = (bf16*)(ws + 30 * MB);

    transpose_w<<<dim3(72, 24), dim3(32, 8), 0, stream>>>(qkv_w,  qkv_wt,  768, 2304);
    transpose_w<<<dim3(24, 24), dim3(32, 8), 0, stream>>>(proj_w, proj_wt, 768, 768);
    transpose_w<<<dim3(96, 24), dim3(32, 8), 0, stream>>>(fc1_w,  fc1_wt,  768, 3072);
    transpose_w<<<dim3(24, 96), dim3(32, 8), 0, stream>>>(fc2_w,  fc2_wt,  3072, 768);

    ln1_window_kernel<<<9800, 256, 0, stream>>>(x, n1w, n1b, xw);
    mfma_gemm<0><<<dim3(18, 77), 256, 0, stream>>>(
        xw, qkv_wt, qkv_b, qkvb, nullptr, nullptr, nullptr, 9800, 2304, 768);
    attn_kernel<<<600, 256, 0, stream>>>(qkvb, rph, rpw, att);
    mfma_gemm<1><<<dim3(6, 77), 256, 0, stream>>>(
        att, proj_wt, proj_b, nullptr, y, x, nullptr, 9800, 768, 768);
    ln2_kernel<<<8192, 256, 0, stream>>>(y, n2w, n2b, xn2);
    mfma_gemm<2><<<dim3(24, 64), 256, 0, stream>>>(
        xn2, fc1_wt, fc1_b, h, nullptr, nullptr, nullptr, 8192, 3072, 768);
    mfma_gemm<3><<<dim3(6, 64), 256, 0, stream>>>(
        h, fc2_wt, fc2_b, nullptr, out, nullptr, y, 8192, 768, 3072);
}

// Round 5
// 466.382 us; speedup vs baseline: 5.5646x; 1.0398x over previous
//
#include <hip/hip_runtime.h>
#include <hip/hip_bf16.h>
#include <math.h>

typedef __hip_bfloat16 bf16;
typedef __attribute__((ext_vector_type(8))) short short8;
typedef __attribute__((ext_vector_type(4))) float f32x4;

__device__ __forceinline__ float b2f(bf16 v) { return __bfloat162float(v); }
__device__ __forceinline__ bf16 f2b(float f) { return __float2bfloat16(f); }

// ---------------------------------------------------------------------------
// K0: all 4 weight transposes (fp32 KxN -> bf16 NxK) in one launch.
// blocks: [0,1728) qkv | [1728,2304) proj | [2304,4608) fc1 | [4608,6912) fc2
// ---------------------------------------------------------------------------
__launch_bounds__(256)
__global__ void transpose_all(const float* __restrict__ qkv_w,
                              const float* __restrict__ proj_w,
                              const float* __restrict__ fc1_w,
                              const float* __restrict__ fc2_w,
                              bf16* __restrict__ qkv_wt,
                              bf16* __restrict__ proj_wt,
                              bf16* __restrict__ fc1_wt,
                              bf16* __restrict__ fc2_wt)
{
    __shared__ float t[32][33];
    int id = blockIdx.x;
    const float* W; bf16* Wt; int K, N, tix, tiy;
    if (id < 1728)      { W = qkv_w;  Wt = qkv_wt;  K = 768;  N = 2304; tix = id % 72;           tiy = id / 72; }
    else if (id < 2304) { W = proj_w; Wt = proj_wt; K = 768;  N = 768;  tix = (id - 1728) % 24;  tiy = (id - 1728) / 24; }
    else if (id < 4608) { W = fc1_w;  Wt = fc1_wt;  K = 768;  N = 3072; tix = (id - 2304) % 96;  tiy = (id - 2304) / 96; }
    else                { W = fc2_w;  Wt = fc2_wt;  K = 3072; N = 768;  tix = (id - 4608) % 24;  tiy = (id - 4608) / 24; }
    int n0 = tix * 32, k0 = tiy * 32;
    int tx = threadIdx.x & 31, ty = threadIdx.x >> 5;   // 32 x 8
    #pragma unroll
    for (int i = 0; i < 4; i++)
        t[ty * 4 + i][tx] = W[(size_t)(k0 + ty * 4 + i) * N + n0 + tx];
    __syncthreads();
    #pragma unroll
    for (int i = 0; i < 4; i++)
        Wt[(size_t)(n0 + ty * 4 + i) * K + k0 + tx] = f2b(t[tx][ty * 4 + i]);
}

// ---------------------------------------------------------------------------
// K0b: fill vt padded-key slots with v_bias; convert qkv_b -> bf16.
// blocks 0..599 = (bwi, head); block 600 converts qkv_b.
// ---------------------------------------------------------------------------
__launch_bounds__(256)
__global__ void fill_kernel(const float* __restrict__ qkv_b,
                            bf16* __restrict__ vt,
                            bf16* __restrict__ bias_bf)
{
    int blk = blockIdx.x;
    int tid = threadIdx.x;
    if (blk == 600) {
        for (int c = tid; c < 2304; c += 256) bias_bf[c] = f2b(qkv_b[c]);
        return;
    }
    int bwi = blk / 12, head = blk % 12;
    int wq = bwi % 25;
    int hi = ((wq / 5) == 4) ? 8 : 14;
    int wi = ((wq % 5) == 4) ? 8 : 14;
    if (hi == 14 && wi == 14) return;
    size_t base = (size_t)(bwi * 12 + head) * 64 * 196;
    for (int t = tid; t < 196 * 64; t += 256) {
        int d = t & 63, key = t >> 6;
        int i = key / 14, j = key % 14;
        if (i >= hi || j >= wi)
            vt[base + (size_t)d * 196 + key] = f2b(qkv_b[1536 + head * 64 + d]);
    }
}

// ---------------------------------------------------------------------------
// K1/K5: LayerNorm (fp32 in, 768 cols) -> bf16 out. Used for LN1 and LN2.
// ---------------------------------------------------------------------------
__launch_bounds__(256)
__global__ void ln_kernel(const float* __restrict__ y,
                          const float* __restrict__ wgt,
                          const float* __restrict__ bia,
                          bf16* __restrict__ xn)
{
    int blk = blockIdx.x;
    const float* yin = y + (size_t)blk * 768;
    bf16* out = xn + (size_t)blk * 768;
    int tid = threadIdx.x;
    float v[3]; float s = 0.f, ss = 0.f;
    #pragma unroll
    for (int t = 0; t < 3; t++) {
        float f = yin[tid + t * 256];
        v[t] = f; s += f; ss += f * f;
    }
    #pragma unroll
    for (int o = 32; o > 0; o >>= 1) { s += __shfl_xor(s, o); ss += __shfl_xor(ss, o); }
    __shared__ float red[8];
    int w = tid >> 6, lane = tid & 63;
    if (lane == 0) { red[w] = s; red[4 + w] = ss; }
    __syncthreads();
    s  = red[0] + red[1] + red[2] + red[3];
    ss = red[4] + red[5] + red[6] + red[7];
    float mu = s * (1.0f / 768.0f);
    float var = ss * (1.0f / 768.0f) - mu * mu;
    float rs = rsqrtf(var + 1e-5f);
    #pragma unroll
    for (int t = 0; t < 3; t++) {
        int c = tid + t * 256;
        out[c] = f2b((v[t] - mu) * rs * wgt[c] + bia[c]);
    }
}

// ---------------------------------------------------------------------------
// MFMA GEMM (m97 structure): C = A(M x K) @ Bt^T + bias. M multiple of 128.
//  EPI 0: qkv — Q/K cols -> natural outb; V cols -> scatter to vt (transposed)
//  EPI 1: proj — outf = xres + C (natural rows, f32)
//  EPI 2: fc1 — exact GELU, bf16
//  EPI 3: fc2 — outf = yres + C (f32, d_out)
// ---------------------------------------------------------------------------
template<int EPI>
__launch_bounds__(256)
__global__ void mfma_gemm(const bf16* __restrict__ A,
                          const bf16* __restrict__ Bt,
                          const float* __restrict__ bias,
                          bf16* __restrict__ outb,
                          float* __restrict__ outf,
                          const float* __restrict__ xres,
                          const float* __restrict__ yres,
                          bf16* __restrict__ vtg,
                          int M, int N, int K)
{
    __shared__ bf16 As[128 * 32];
    __shared__ bf16 Bs[128 * 32];
    const int tid = threadIdx.x;
    const int w = tid >> 6, lane = tid & 63;
    const int wm = (w & 1) * 64, wn = (w >> 1) * 64;
    const int tm = blockIdx.y * 128, tn = blockIdx.x * 128;

    f32x4 acc[4][4] = {};

    for (int k0 = 0; k0 < K; k0 += 32) {
        #pragma unroll
        for (int i = 0; i < 2; i++) {
            int e = i * 256 + tid;
            int r = e >> 2, ch = e & 3;
            __builtin_amdgcn_global_load_lds(
                (const __attribute__((address_space(1))) unsigned*)(A + (size_t)(tm + r) * K + k0 + ch * 8),
                (__attribute__((address_space(3))) unsigned*)(As + e * 8),
                16, 0, 0);
            __builtin_amdgcn_global_load_lds(
                (const __attribute__((address_space(1))) unsigned*)(Bt + (size_t)(tn + r) * K + k0 + ch * 8),
                (__attribute__((address_space(3))) unsigned*)(Bs + e * 8),
                16, 0, 0);
        }
        __syncthreads();
        short8 af[4], bfr[4];
        #pragma unroll
        for (int mi = 0; mi < 4; mi++)
            af[mi] = *(const short8*)(As + (wm + mi * 16 + (lane & 15)) * 32 + (lane >> 4) * 8);
        #pragma unroll
        for (int ni = 0; ni < 4; ni++)
            bfr[ni] = *(const short8*)(Bs + (wn + ni * 16 + (lane & 15)) * 32 + (lane >> 4) * 8);
        #pragma unroll
        for (int mi = 0; mi < 4; mi++)
            #pragma unroll
            for (int ni = 0; ni < 4; ni++)
                acc[mi][ni] = __builtin_amdgcn_mfma_f32_16x16x32_bf16(
                    af[mi], bfr[ni], acc[mi][ni], 0, 0, 0);
        __syncthreads();
    }

    const int col_l = lane & 15, row_l = (lane >> 4) * 4;
    float bv[4];
    #pragma unroll
    for (int ni = 0; ni < 4; ni++) bv[ni] = bias[tn + wn + ni * 16 + col_l];

    #pragma unroll
    for (int mi = 0; mi < 4; mi++) {
        #pragma unroll
        for (int r = 0; r < 4; r++) {
            int gm = tm + wm + mi * 16 + row_l + r;
            if (EPI == 0) {
                // token map for V scatter
                int bb = gm >> 12, rr = (gm >> 6) & 63, cc = gm & 63;
                int wh = rr / 14, ii = rr - wh * 14;
                int ww2 = cc / 14, jj = cc - ww2 * 14;
                size_t vrow = (size_t)((bb * 25 + wh * 5 + ww2) * 12) * 64;
                int key = ii * 14 + jj;
                #pragma unroll
                for (int ni = 0; ni < 4; ni++) {
                    int gn = tn + wn + ni * 16 + col_l;
                    float v = acc[mi][ni][r] + bv[ni];
                    if (gn < 1536) {
                        outb[(size_t)gm * 2304 + gn] = f2b(v);
                    } else {
                        int hv = gn - 1536;
                        vtg[(vrow + ((hv >> 6) * 64 + (hv & 63))) * 196 + key] = f2b(v);
                    }
                }
            } else if (EPI == 1) {
                #pragma unroll
                for (int ni = 0; ni < 4; ni++) {
                    int gn = tn + wn + ni * 16 + col_l;
                    outf[(size_t)gm * 768 + gn] =
                        xres[(size_t)gm * 768 + gn] + acc[mi][ni][r] + bv[ni];
                }
            } else if (EPI == 2) {
                #pragma unroll
                for (int ni = 0; ni < 4; ni++) {
                    int gn = tn + wn + ni * 16 + col_l;
                    float v = acc[mi][ni][r] + bv[ni];
                    outb[(size_t)gm * N + gn] =
                        f2b(0.5f * v * (1.0f + erff(v * 0.70710678118654752f)));
                }
            } else {
                #pragma unroll
                for (int ni = 0; ni < 4; ni++) {
                    int gn = tn + wn + ni * 16 + col_l;
                    outf[(size_t)gm * 768 + gn] =
                        yres[(size_t)gm * 768 + gn] + acc[mi][ni][r] + bv[ni];
                }
            }
        }
    }
}

// ---------------------------------------------------------------------------
// K3: fused MFMA windowed attention (natural-layout I/O).
// One block per (window, head), 4 waves, LDS 77312 B -> 2 blocks/CU.
// B matrix (272x64) = [K 0..207 | Rh table 208..239 | Rw table 240..271].
// V comes pre-transposed from vt (d x key). P done in per-ks 16x32 slices.
// ---------------------------------------------------------------------------
__launch_bounds__(256)
__global__ void attn_kernel(const bf16* __restrict__ qkv,
                            const bf16* __restrict__ vtg,
                            const bf16* __restrict__ bias_bf,
                            const float* __restrict__ rel_h,
                            const float* __restrict__ rel_w,
                            bf16* __restrict__ att)
{
    __shared__ bf16 BsLo[272 * 32];
    __shared__ bf16 BsHi[272 * 32];
    __shared__ bf16 Vt[64 * 232];        // stride 232, cols 196..231 zero
    __shared__ bf16 Ps[4][16 * 36];      // per-wave 16x32 P slice, stride 36
    __shared__ bf16 relS[4][2][16 * 32]; // per-wave q.relTable (bf16)

    int bh = blockIdx.x;                 // 0..599
    int bwi = bh / 12, head = bh % 12;
    int tid = threadIdx.x, w = tid >> 6, lane = tid & 63;
    int b = bwi / 25, wq = bwi % 25;
    int r0 = (wq / 5) * 14, c0 = (wq % 5) * 14;

    // zero B rows 196..271
    for (int idx = tid; idx < 76 * 16; idx += 256) {
        int r = 196 + (idx >> 4), cd = idx & 15;
        ((unsigned*)BsLo)[r * 16 + cd] = 0u;
        ((unsigned*)BsHi)[r * 16 + cd] = 0u;
    }
    // K rows 0..195: gather valid token row or bf16 bias
    for (int idx = tid; idx < 196 * 32; idx += 256) {
        int m = idx >> 5, c2 = idx & 31;
        int i = m / 14, j = m % 14;
        int rr = r0 + i, cc = c0 + j;
        const bf16* src = (rr < 64 && cc < 64)
            ? qkv + ((size_t)((b << 12) + rr * 64 + cc) * 2304 + 768 + head * 64)
            : bias_bf + 768 + head * 64;
        unsigned u = *(const unsigned*)(src + 2 * c2);
        if (c2 < 16) ((unsigned*)BsLo)[m * 16 + c2] = u;
        else         ((unsigned*)BsHi)[m * 16 + (c2 - 16)] = u;
    }
    // rel tables fp32 -> bf16 into rows 208.. / 240..
    for (int idx = tid; idx < 27 * 32; idx += 256) {
        int t = idx >> 5, c2 = idx & 31;
        float2 h2 = *(const float2*)(rel_h + t * 64 + 2 * c2);
        float2 w2 = *(const float2*)(rel_w + t * 64 + 2 * c2);
        bf16 hb[2] = { f2b(h2.x), f2b(h2.y) };
        bf16 wb[2] = { f2b(w2.x), f2b(w2.y) };
        int r1 = 208 + t, r2 = 240 + t;
        if (c2 < 16) {
            ((unsigned*)BsLo)[r1 * 16 + c2] = *(unsigned*)hb;
            ((unsigned*)BsLo)[r2 * 16 + c2] = *(unsigned*)wb;
        } else {
            ((unsigned*)BsHi)[r1 * 16 + c2 - 16] = *(unsigned*)hb;
            ((unsigned*)BsHi)[r2 * 16 + c2 - 16] = *(unsigned*)wb;
        }
    }
    // Vt: zero cols 196..231, stage keys 0..195 (contiguous dwords)
    for (int idx = tid; idx < 64 * 18; idx += 256) {
        int d = idx / 18, cd = idx % 18;
        ((unsigned*)Vt)[d * 116 + 98 + cd] = 0u;
    }
    {
        const bf16* vrow = vtg + (size_t)(bwi * 12 + head) * 64 * 196;
        for (int idx = tid; idx < 64 * 98; idx += 256) {
            int d = idx / 98, kp = idx % 98;
            ((unsigned*)Vt)[d * 116 + kp] = *(const unsigned*)(vrow + (size_t)d * 196 + 2 * kp);
        }
    }
    __syncthreads();

    const int cl = lane & 15, rg = lane >> 4;
    const int lr0 = rg * 4;

    for (int mt = w; mt < 13; mt += 4) {
        // Q A-frags from global (or bias row for padded queries)
        int q0 = mt * 16 + cl;
        int qi = q0 / 14, qj = q0 % 14;
        int qr = r0 + qi, qc = c0 + qj;
        bool qv = (q0 < 196) && (qr < 64) && (qc < 64);
        const bf16* qp = qv
            ? qkv + ((size_t)((b << 12) + qr * 64 + qc) * 2304 + head * 64 + rg * 8)
            : bias_bf + head * 64 + rg * 8;
        short8 af0 = *(const short8*)(qp);
        short8 af1 = *(const short8*)(qp + 32);

        // QK + rel scores: 17 n-tiles
        f32x4 sc[17];
        #pragma unroll
        for (int ni = 0; ni < 17; ni++) {
            short8 blo = *(const short8*)(BsLo + (ni * 16 + cl) * 32 + rg * 8);
            short8 bhi = *(const short8*)(BsHi + (ni * 16 + cl) * 32 + rg * 8);
            f32x4 t = {};
            t = __builtin_amdgcn_mfma_f32_16x16x32_bf16(af0, blo, t, 0, 0, 0);
            sc[ni] = __builtin_amdgcn_mfma_f32_16x16x32_bf16(af1, bhi, t, 0, 0, 0);
        }
        // rel tiles -> LDS (bf16)
        #pragma unroll
        for (int t = 0; t < 2; t++)
            #pragma unroll
            for (int r = 0; r < 4; r++) {
                relS[w][0][(lr0 + r) * 32 + t * 16 + cl] = f2b(sc[13 + t][r]);
                relS[w][1][(lr0 + r) * 32 + t * 16 + cl] = f2b(sc[15 + t][r]);
            }
        __builtin_amdgcn_wave_barrier();

        // softmax
        int iq[4], jq[4];
        #pragma unroll
        for (int r = 0; r < 4; r++) { int q = mt * 16 + lr0 + r; iq[r] = q / 14; jq[r] = q % 14; }
        float mx[4] = { -1e30f, -1e30f, -1e30f, -1e30f };
        #pragma unroll
        for (int ni = 0; ni < 13; ni++) {
            int c = ni * 16 + cl;
            int kh = c / 14; if (kh > 13) kh = 13;
            int kw = c - (c / 14) * 14;
            bool valid = c < 196;
            #pragma unroll
            for (int r = 0; r < 4; r++) {
                float lg = sc[ni][r] * 0.125f
                         + b2f(relS[w][0][(lr0 + r) * 32 + iq[r] - kh + 13])
                         + b2f(relS[w][1][(lr0 + r) * 32 + jq[r] - kw + 13]);
                sc[ni][r] = valid ? lg : -1e30f;
                mx[r] = fmaxf(mx[r], sc[ni][r]);
            }
        }
        float sum[4];
        #pragma unroll
        for (int r = 0; r < 4; r++) {
            #pragma unroll
            for (int o = 1; o < 16; o <<= 1) mx[r] = fmaxf(mx[r], __shfl_xor(mx[r], o));
            sum[r] = 0.f;
        }
        #pragma unroll
        for (int ni = 0; ni < 13; ni++)
            #pragma unroll
            for (int r = 0; r < 4; r++) {
                float e = __expf(sc[ni][r] - mx[r]);
                sc[ni][r] = e; sum[r] += e;
            }
        #pragma unroll
        for (int r = 0; r < 4; r++) {
            #pragma unroll
            for (int o = 1; o < 16; o <<= 1) sum[r] += __shfl_xor(sum[r], o);
            sum[r] = 1.0f / sum[r];
        }

        // PV in 7 ks-steps of 32 keys via small per-wave P slice
        f32x4 ov[4] = {};
        #pragma unroll
        for (int ks = 0; ks < 7; ks++) {
            #pragma unroll
            for (int r = 0; r < 4; r++) {
                Ps[w][(lr0 + r) * 36 + cl] = f2b(sc[2 * ks][r] * sum[r]);
                Ps[w][(lr0 + r) * 36 + 16 + cl] =
                    (2 * ks + 1 < 13) ? f2b(sc[2 * ks + 1][r] * sum[r]) : f2b(0.0f);
            }
            __builtin_amdgcn_wave_barrier();
            short8 pa = *(const short8*)(&Ps[w][cl * 36 + rg * 8]);
            #pragma unroll
            for (int ni = 0; ni < 4; ni++) {
                short8 vb = *(const short8*)(Vt + (ni * 16 + cl) * 232 + ks * 32 + rg * 8);
                ov[ni] = __builtin_amdgcn_mfma_f32_16x16x32_bf16(pa, vb, ov[ni], 0, 0, 0);
            }
            __builtin_amdgcn_wave_barrier();
        }

        // store valid q rows to natural att layout
        #pragma unroll
        for (int r = 0; r < 4; r++) {
            int q = mt * 16 + lr0 + r;
            int i = q / 14, j = q % 14;
            int rr = r0 + i, cc = c0 + j;
            if (q < 196 && rr < 64 && cc < 64) {
                size_t ob = (size_t)((b << 12) + rr * 64 + cc) * 768 + head * 64;
                #pragma unroll
                for (int ni = 0; ni < 4; ni++)
                    att[ob + ni * 16 + cl] = f2b(ov[ni][r]);
            }
        }
    }
}

// ---------------------------------------------------------------------------
// Workspace (byte offsets, peak 103 MiB < 113 proven):
//   0        qkv_wt (3.54M) | 3.5M proj_wt (1.18M) | 5M fc1_wt (4.72M)
//   10M      fc2_wt (4.72M) | 14.5M bias_bf (4.6K)
//   15M      B-slot 12.58M: xn1 -> att -> xn2
//   28M      qkv 8192x2304 bf16 (37.7M); later h 8192x3072 bf16 (50.3M)
//   64M      vt 600x64x196 bf16 (15.05M)   [dead after attn; h overlaps]
//   79M      y 8192x768 f32 (25.2M)
// ---------------------------------------------------------------------------
extern "C" void kernel_launch(void* const* d_in, const int* in_sizes, int n_in,
                              void* d_out, int out_size, void* d_ws, size_t ws_size,
                              hipStream_t stream)
{
    const float* x      = (const float*)d_in[0];
    const float* n1w    = (const float*)d_in[1];
    const float* n1b    = (const float*)d_in[2];
    const float* qkv_w  = (const float*)d_in[3];
    const float* qkv_b  = (const float*)d_in[4];
    const float* proj_w = (const float*)d_in[5];
    const float* proj_b = (const float*)d_in[6];
    const float* rph    = (const float*)d_in[7];
    const float* rpw    = (const float*)d_in[8];
    const float* n2w    = (const float*)d_in[9];
    const float* n2b    = (const float*)d_in[10];
    const float* fc1_w  = (const float*)d_in[11];
    const float* fc1_b  = (const float*)d_in[12];
    const float* fc2_w  = (const float*)d_in[13];
    const float* fc2_b  = (const float*)d_in[14];
    float* out = (float*)d_out;

    char* ws = (char*)d_ws;
    const size_t MB = (size_t)1 << 20;
    bf16* qkv_wt  = (bf16*)(ws);
    bf16* proj_wt = (bf16*)(ws + (size_t)(3.5 * MB));
    bf16* fc1_wt  = (bf16*)(ws + 5 * MB);
    bf16* fc2_wt  = (bf16*)(ws + 10 * MB);
    bf16* bias_bf = (bf16*)(ws + (size_t)(14.5 * MB));
    bf16* xn1     = (bf16*)(ws + 15 * MB);
    bf16* att     = (bf16*)(ws + 15 * MB);
    bf16* xn2     = (bf16*)(ws + 15 * MB);
    bf16* qkvb    = (bf16*)(ws + 28 * MB);
    bf16* h       = (bf16*)(ws + 28 * MB);
    bf16* vt      = (bf16*)(ws + 64 * MB);
    float* y      = (float*)(ws + 79 * MB);

    transpose_all<<<6912, 256, 0, stream>>>(qkv_w, proj_w, fc1_w, fc2_w,
                                            qkv_wt, proj_wt, fc1_wt, fc2_wt);
    fill_kernel<<<601, 256, 0, stream>>>(qkv_b, vt, bias_bf);

    // LN1 (natural 8192 rows)
    ln_kernel<<<8192, 256, 0, stream>>>(x, n1w, n1b, xn1);
    // qkv = xn1 @ qkv_w + b; V cols scattered to vt
    mfma_gemm<0><<<dim3(18, 64), 256, 0, stream>>>(
        xn1, qkv_wt, qkv_b, qkvb, nullptr, nullptr, nullptr, vt, 8192, 2304, 768);
    // attention (windowed gather/scatter inside)
    attn_kernel<<<600, 256, 0, stream>>>(qkvb, vt, bias_bf, rph, rpw, att);
    // proj + residual -> y (natural)
    mfma_gemm<1><<<dim3(6, 64), 256, 0, stream>>>(
        att, proj_wt, proj_b, nullptr, y, x, nullptr, nullptr, 8192, 768, 768);
    // LN2
    ln_kernel<<<8192, 256, 0, stream>>>(y, n2w, n2b, xn2);
    // fc1 + gelu
    mfma_gemm<2><<<dim3(24, 64), 256, 0, stream>>>(
        xn2, fc1_wt, fc1_b, h, nullptr, nullptr, nullptr, nullptr, 8192, 3072, 768);
    // fc2 + residual -> out
    mfma_gemm<3><<<dim3(6, 64), 256, 0, stream>>>(
        h, fc2_wt, fc2_b, nullptr, out, nullptr, y, nullptr, 8192, 768, 3072);
}

// Round 6
// 424.993 us; speedup vs baseline: 6.1065x; 1.0974x over previous
//
#include <hip/hip_runtime.h>
#include <hip/hip_bf16.h>
#include <math.h>

typedef __hip_bfloat16 bf16;
typedef __attribute__((ext_vector_type(8))) short short8;
typedef __attribute__((ext_vector_type(4))) float f32x4;

__device__ __forceinline__ float b2f(bf16 v) { return __bfloat162float(v); }
__device__ __forceinline__ bf16 f2b(float f) { return __float2bfloat16(f); }

// ---------------------------------------------------------------------------
// K0: all 4 weight transposes (fp32 KxN -> bf16 NxK) in one launch.
// ---------------------------------------------------------------------------
__launch_bounds__(256)
__global__ void transpose_all(const float* __restrict__ qkv_w,
                              const float* __restrict__ proj_w,
                              const float* __restrict__ fc1_w,
                              const float* __restrict__ fc2_w,
                              bf16* __restrict__ qkv_wt,
                              bf16* __restrict__ proj_wt,
                              bf16* __restrict__ fc1_wt,
                              bf16* __restrict__ fc2_wt)
{
    __shared__ float t[32][33];
    int id = blockIdx.x;
    const float* W; bf16* Wt; int K, N, tix, tiy;
    if (id < 1728)      { W = qkv_w;  Wt = qkv_wt;  K = 768;  N = 2304; tix = id % 72;           tiy = id / 72; }
    else if (id < 2304) { W = proj_w; Wt = proj_wt; K = 768;  N = 768;  tix = (id - 1728) % 24;  tiy = (id - 1728) / 24; }
    else if (id < 4608) { W = fc1_w;  Wt = fc1_wt;  K = 768;  N = 3072; tix = (id - 2304) % 96;  tiy = (id - 2304) / 96; }
    else                { W = fc2_w;  Wt = fc2_wt;  K = 3072; N = 768;  tix = (id - 4608) % 24;  tiy = (id - 4608) / 24; }
    int n0 = tix * 32, k0 = tiy * 32;
    int tx = threadIdx.x & 31, ty = threadIdx.x >> 5;   // 32 x 8
    #pragma unroll
    for (int i = 0; i < 4; i++)
        t[ty * 4 + i][tx] = W[(size_t)(k0 + ty * 4 + i) * N + n0 + tx];
    __syncthreads();
    #pragma unroll
    for (int i = 0; i < 4; i++)
        Wt[(size_t)(n0 + ty * 4 + i) * K + k0 + tx] = f2b(t[tx][ty * 4 + i]);
}

// ---------------------------------------------------------------------------
// K0b: fill vt padded-key slots with v_bias; convert qkv_b -> bf16.
// ---------------------------------------------------------------------------
__launch_bounds__(256)
__global__ void fill_kernel(const float* __restrict__ qkv_b,
                            bf16* __restrict__ vt,
                            bf16* __restrict__ bias_bf)
{
    int blk = blockIdx.x;
    int tid = threadIdx.x;
    if (blk == 600) {
        for (int c = tid; c < 2304; c += 256) bias_bf[c] = f2b(qkv_b[c]);
        return;
    }
    int bwi = blk / 12, head = blk % 12;
    int wq = bwi % 25;
    int hi = ((wq / 5) == 4) ? 8 : 14;
    int wi = ((wq % 5) == 4) ? 8 : 14;
    if (hi == 14 && wi == 14) return;
    size_t base = (size_t)(bwi * 12 + head) * 64 * 196;
    for (int t = tid; t < 196 * 64; t += 256) {
        int d = t & 63, key = t >> 6;
        int i = key / 14, j = key % 14;
        if (i >= hi || j >= wi)
            vt[base + (size_t)d * 196 + key] = f2b(qkv_b[1536 + head * 64 + d]);
    }
}

// ---------------------------------------------------------------------------
// K1/K5: LayerNorm (fp32 in, 768 cols) -> bf16 out.
// ---------------------------------------------------------------------------
__launch_bounds__(256)
__global__ void ln_kernel(const float* __restrict__ y,
                          const float* __restrict__ wgt,
                          const float* __restrict__ bia,
                          bf16* __restrict__ xn)
{
    int blk = blockIdx.x;
    const float* yin = y + (size_t)blk * 768;
    bf16* out = xn + (size_t)blk * 768;
    int tid = threadIdx.x;
    float v[3]; float s = 0.f, ss = 0.f;
    #pragma unroll
    for (int t = 0; t < 3; t++) {
        float f = yin[tid + t * 256];
        v[t] = f; s += f; ss += f * f;
    }
    #pragma unroll
    for (int o = 32; o > 0; o >>= 1) { s += __shfl_xor(s, o); ss += __shfl_xor(ss, o); }
    __shared__ float red[8];
    int w = tid >> 6, lane = tid & 63;
    if (lane == 0) { red[w] = s; red[4 + w] = ss; }
    __syncthreads();
    s  = red[0] + red[1] + red[2] + red[3];
    ss = red[4] + red[5] + red[6] + red[7];
    float mu = s * (1.0f / 768.0f);
    float var = ss * (1.0f / 768.0f) - mu * mu;
    float rs = rsqrtf(var + 1e-5f);
    #pragma unroll
    for (int t = 0; t < 3; t++) {
        int c = tid + t * 256;
        out[c] = f2b((v[t] - mu) * rs * wgt[c] + bia[c]);
    }
}

// ---------------------------------------------------------------------------
// MFMA GEMM: C = A(M x K) @ Bt^T + bias.  BK=64 as two BK=32 LDS buffers
// (keeps the verified conflict-free fragment layout; halves barrier count).
// BM template: 128 (qkv/fc1) or 64 (proj/fc2 -> 2x grid, 32 AGPRs, ~4 blk/CU).
//  EPI 0: qkv — Q/K cols -> natural outb; V cols -> scatter to vt (transposed)
//  EPI 1: proj — outf = xres + C (f32)
//  EPI 2: fc1 — exact GELU, bf16
//  EPI 3: fc2 — outf = yres + C (f32, d_out)
// ---------------------------------------------------------------------------
template<int EPI, int BM>
__launch_bounds__(256)
__global__ void mfma_gemm(const bf16* __restrict__ A,
                          const bf16* __restrict__ Bt,
                          const float* __restrict__ bias,
                          bf16* __restrict__ outb,
                          float* __restrict__ outf,
                          const float* __restrict__ xres,
                          const float* __restrict__ yres,
                          bf16* __restrict__ vtg,
                          int M, int N, int K)
{
    constexpr int MI = BM / 32;          // m-frags per wave
    __shared__ bf16 As0[BM * 32];
    __shared__ bf16 As1[BM * 32];
    __shared__ bf16 Bs0[128 * 32];
    __shared__ bf16 Bs1[128 * 32];
    const int tid = threadIdx.x;
    const int w = tid >> 6, lane = tid & 63;
    const int cl = lane & 15, rg = lane >> 4;
    const int wm = (w & 1) * (BM / 2), wn = (w >> 1) * 64;
    const int tm = blockIdx.y * BM, tn = blockIdx.x * 128;

    f32x4 acc[MI][4] = {};

    for (int k0 = 0; k0 < K; k0 += 64) {
        #pragma unroll
        for (int i = 0; i < BM / 64; i++) {
            int e = i * 256 + tid;
            int r = e >> 2, ch = e & 3;
            const bf16* ap = A + (size_t)(tm + r) * K + k0 + ch * 8;
            __builtin_amdgcn_global_load_lds(
                (const __attribute__((address_space(1))) unsigned*)(ap),
                (__attribute__((address_space(3))) unsigned*)(As0 + e * 8), 16, 0, 0);
            __builtin_amdgcn_global_load_lds(
                (const __attribute__((address_space(1))) unsigned*)(ap + 32),
                (__attribute__((address_space(3))) unsigned*)(As1 + e * 8), 16, 0, 0);
        }
        #pragma unroll
        for (int i = 0; i < 2; i++) {
            int e = i * 256 + tid;
            int r = e >> 2, ch = e & 3;
            const bf16* bp = Bt + (size_t)(tn + r) * K + k0 + ch * 8;
            __builtin_amdgcn_global_load_lds(
                (const __attribute__((address_space(1))) unsigned*)(bp),
                (__attribute__((address_space(3))) unsigned*)(Bs0 + e * 8), 16, 0, 0);
            __builtin_amdgcn_global_load_lds(
                (const __attribute__((address_space(1))) unsigned*)(bp + 32),
                (__attribute__((address_space(3))) unsigned*)(Bs1 + e * 8), 16, 0, 0);
        }
        __syncthreads();
        #pragma unroll
        for (int kk = 0; kk < 2; kk++) {
            const bf16* Ab = kk ? As1 : As0;
            const bf16* Bb = kk ? Bs1 : Bs0;
            short8 af[MI], bfr[4];
            #pragma unroll
            for (int mi = 0; mi < MI; mi++)
                af[mi] = *(const short8*)(Ab + (wm + mi * 16 + cl) * 32 + rg * 8);
            #pragma unroll
            for (int ni = 0; ni < 4; ni++)
                bfr[ni] = *(const short8*)(Bb + (wn + ni * 16 + cl) * 32 + rg * 8);
            #pragma unroll
            for (int mi = 0; mi < MI; mi++)
                #pragma unroll
                for (int ni = 0; ni < 4; ni++)
                    acc[mi][ni] = __builtin_amdgcn_mfma_f32_16x16x32_bf16(
                        af[mi], bfr[ni], acc[mi][ni], 0, 0, 0);
        }
        __syncthreads();
    }

    const int row_l = rg * 4;
    float bv[4];
    #pragma unroll
    for (int ni = 0; ni < 4; ni++) bv[ni] = bias[tn + wn + ni * 16 + cl];

    #pragma unroll
    for (int mi = 0; mi < MI; mi++) {
        #pragma unroll
        for (int r = 0; r < 4; r++) {
            int gm = tm + wm + mi * 16 + row_l + r;
            if (EPI == 0) {
                int bb = gm >> 12, rr = (gm >> 6) & 63, cc = gm & 63;
                int wh = rr / 14, ii = rr - wh * 14;
                int ww2 = cc / 14, jj = cc - ww2 * 14;
                size_t vrow = (size_t)((bb * 25 + wh * 5 + ww2) * 12) * 64;
                int key = ii * 14 + jj;
                #pragma unroll
                for (int ni = 0; ni < 4; ni++) {
                    int gn = tn + wn + ni * 16 + cl;
                    float v = acc[mi][ni][r] + bv[ni];
                    if (gn < 1536) {
                        outb[(size_t)gm * 2304 + gn] = f2b(v);
                    } else {
                        int hv = gn - 1536;
                        vtg[(vrow + ((hv >> 6) * 64 + (hv & 63))) * 196 + key] = f2b(v);
                    }
                }
            } else if (EPI == 1) {
                #pragma unroll
                for (int ni = 0; ni < 4; ni++) {
                    int gn = tn + wn + ni * 16 + cl;
                    outf[(size_t)gm * 768 + gn] =
                        xres[(size_t)gm * 768 + gn] + acc[mi][ni][r] + bv[ni];
                }
            } else if (EPI == 2) {
                #pragma unroll
                for (int ni = 0; ni < 4; ni++) {
                    int gn = tn + wn + ni * 16 + cl;
                    float v = acc[mi][ni][r] + bv[ni];
                    outb[(size_t)gm * N + gn] =
                        f2b(0.5f * v * (1.0f + erff(v * 0.70710678118654752f)));
                }
            } else {
                #pragma unroll
                for (int ni = 0; ni < 4; ni++) {
                    int gn = tn + wn + ni * 16 + cl;
                    outf[(size_t)gm * 768 + gn] =
                        yres[(size_t)gm * 768 + gn] + acc[mi][ni][r] + bv[ni];
                }
            }
        }
    }
}

// ---------------------------------------------------------------------------
// K3: fused MFMA windowed attention (unchanged from round 5).
// ---------------------------------------------------------------------------
__launch_bounds__(256)
__global__ void attn_kernel(const bf16* __restrict__ qkv,
                            const bf16* __restrict__ vtg,
                            const bf16* __restrict__ bias_bf,
                            const float* __restrict__ rel_h,
                            const float* __restrict__ rel_w,
                            bf16* __restrict__ att)
{
    __shared__ bf16 BsLo[272 * 32];
    __shared__ bf16 BsHi[272 * 32];
    __shared__ bf16 Vt[64 * 232];
    __shared__ bf16 Ps[4][16 * 36];
    __shared__ bf16 relS[4][2][16 * 32];

    int bh = blockIdx.x;
    int bwi = bh / 12, head = bh % 12;
    int tid = threadIdx.x, w = tid >> 6, lane = tid & 63;
    int b = bwi / 25, wq = bwi % 25;
    int r0 = (wq / 5) * 14, c0 = (wq % 5) * 14;

    for (int idx = tid; idx < 76 * 16; idx += 256) {
        int r = 196 + (idx >> 4), cd = idx & 15;
        ((unsigned*)BsLo)[r * 16 + cd] = 0u;
        ((unsigned*)BsHi)[r * 16 + cd] = 0u;
    }
    for (int idx = tid; idx < 196 * 32; idx += 256) {
        int m = idx >> 5, c2 = idx & 31;
        int i = m / 14, j = m % 14;
        int rr = r0 + i, cc = c0 + j;
        const bf16* src = (rr < 64 && cc < 64)
            ? qkv + ((size_t)((b << 12) + rr * 64 + cc) * 2304 + 768 + head * 64)
            : bias_bf + 768 + head * 64;
        unsigned u = *(const unsigned*)(src + 2 * c2);
        if (c2 < 16) ((unsigned*)BsLo)[m * 16 + c2] = u;
        else         ((unsigned*)BsHi)[m * 16 + (c2 - 16)] = u;
    }
    for (int idx = tid; idx < 27 * 32; idx += 256) {
        int t = idx >> 5, c2 = idx & 31;
        float2 h2 = *(const float2*)(rel_h + t * 64 + 2 * c2);
        float2 w2 = *(const float2*)(rel_w + t * 64 + 2 * c2);
        bf16 hb[2] = { f2b(h2.x), f2b(h2.y) };
        bf16 wb[2] = { f2b(w2.x), f2b(w2.y) };
        int r1 = 208 + t, r2 = 240 + t;
        if (c2 < 16) {
            ((unsigned*)BsLo)[r1 * 16 + c2] = *(unsigned*)hb;
            ((unsigned*)BsLo)[r2 * 16 + c2] = *(unsigned*)wb;
        } else {
            ((unsigned*)BsHi)[r1 * 16 + c2 - 16] = *(unsigned*)hb;
            ((unsigned*)BsHi)[r2 * 16 + c2 - 16] = *(unsigned*)wb;
        }
    }
    for (int idx = tid; idx < 64 * 18; idx += 256) {
        int d = idx / 18, cd = idx % 18;
        ((unsigned*)Vt)[d * 116 + 98 + cd] = 0u;
    }
    {
        const bf16* vrow = vtg + (size_t)(bwi * 12 + head) * 64 * 196;
        for (int idx = tid; idx < 64 * 98; idx += 256) {
            int d = idx / 98, kp = idx % 98;
            ((unsigned*)Vt)[d * 116 + kp] = *(const unsigned*)(vrow + (size_t)d * 196 + 2 * kp);
        }
    }
    __syncthreads();

    const int cl = lane & 15, rg = lane >> 4;
    const int lr0 = rg * 4;

    for (int mt = w; mt < 13; mt += 4) {
        int q0 = mt * 16 + cl;
        int qi = q0 / 14, qj = q0 % 14;
        int qr = r0 + qi, qc = c0 + qj;
        bool qv = (q0 < 196) && (qr < 64) && (qc < 64);
        const bf16* qp = qv
            ? qkv + ((size_t)((b << 12) + qr * 64 + qc) * 2304 + head * 64 + rg * 8)
            : bias_bf + head * 64 + rg * 8;
        short8 af0 = *(const short8*)(qp);
        short8 af1 = *(const short8*)(qp + 32);

        f32x4 sc[17];
        #pragma unroll
        for (int ni = 0; ni < 17; ni++) {
            short8 blo = *(const short8*)(BsLo + (ni * 16 + cl) * 32 + rg * 8);
            short8 bhi = *(const short8*)(BsHi + (ni * 16 + cl) * 32 + rg * 8);
            f32x4 t = {};
            t = __builtin_amdgcn_mfma_f32_16x16x32_bf16(af0, blo, t, 0, 0, 0);
            sc[ni] = __builtin_amdgcn_mfma_f32_16x16x32_bf16(af1, bhi, t, 0, 0, 0);
        }
        #pragma unroll
        for (int t = 0; t < 2; t++)
            #pragma unroll
            for (int r = 0; r < 4; r++) {
                relS[w][0][(lr0 + r) * 32 + t * 16 + cl] = f2b(sc[13 + t][r]);
                relS[w][1][(lr0 + r) * 32 + t * 16 + cl] = f2b(sc[15 + t][r]);
            }
        __builtin_amdgcn_wave_barrier();

        int iq[4], jq[4];
        #pragma unroll
        for (int r = 0; r < 4; r++) { int q = mt * 16 + lr0 + r; iq[r] = q / 14; jq[r] = q % 14; }
        float mx[4] = { -1e30f, -1e30f, -1e30f, -1e30f };
        #pragma unroll
        for (int ni = 0; ni < 13; ni++) {
            int c = ni * 16 + cl;
            int kh = c / 14; if (kh > 13) kh = 13;
            int kw = c - (c / 14) * 14;
            bool valid = c < 196;
            #pragma unroll
            for (int r = 0; r < 4; r++) {
                float lg = sc[ni][r] * 0.125f
                         + b2f(relS[w][0][(lr0 + r) * 32 + iq[r] - kh + 13])
                         + b2f(relS[w][1][(lr0 + r) * 32 + jq[r] - kw + 13]);
                sc[ni][r] = valid ? lg : -1e30f;
                mx[r] = fmaxf(mx[r], sc[ni][r]);
            }
        }
        float sum[4];
        #pragma unroll
        for (int r = 0; r < 4; r++) {
            #pragma unroll
            for (int o = 1; o < 16; o <<= 1) mx[r] = fmaxf(mx[r], __shfl_xor(mx[r], o));
            sum[r] = 0.f;
        }
        #pragma unroll
        for (int ni = 0; ni < 13; ni++)
            #pragma unroll
            for (int r = 0; r < 4; r++) {
                float e = __expf(sc[ni][r] - mx[r]);
                sc[ni][r] = e; sum[r] += e;
            }
        #pragma unroll
        for (int r = 0; r < 4; r++) {
            #pragma unroll
            for (int o = 1; o < 16; o <<= 1) sum[r] += __shfl_xor(sum[r], o);
            sum[r] = 1.0f / sum[r];
        }

        f32x4 ov[4] = {};
        #pragma unroll
        for (int ks = 0; ks < 7; ks++) {
            #pragma unroll
            for (int r = 0; r < 4; r++) {
                Ps[w][(lr0 + r) * 36 + cl] = f2b(sc[2 * ks][r] * sum[r]);
                Ps[w][(lr0 + r) * 36 + 16 + cl] =
                    (2 * ks + 1 < 13) ? f2b(sc[2 * ks + 1][r] * sum[r]) : f2b(0.0f);
            }
            __builtin_amdgcn_wave_barrier();
            short8 pa = *(const short8*)(&Ps[w][cl * 36 + rg * 8]);
            #pragma unroll
            for (int ni = 0; ni < 4; ni++) {
                short8 vb = *(const short8*)(Vt + (ni * 16 + cl) * 232 + ks * 32 + rg * 8);
                ov[ni] = __builtin_amdgcn_mfma_f32_16x16x32_bf16(pa, vb, ov[ni], 0, 0, 0);
            }
            __builtin_amdgcn_wave_barrier();
        }

        #pragma unroll
        for (int r = 0; r < 4; r++) {
            int q = mt * 16 + lr0 + r;
            int i = q / 14, j = q % 14;
            int rr = r0 + i, cc = c0 + j;
            if (q < 196 && rr < 64 && cc < 64) {
                size_t ob = (size_t)((b << 12) + rr * 64 + cc) * 768 + head * 64;
                #pragma unroll
                for (int ni = 0; ni < 4; ni++)
                    att[ob + ni * 16 + cl] = f2b(ov[ni][r]);
            }
        }
    }
}

// ---------------------------------------------------------------------------
// Workspace layout unchanged from round 5 (peak ~104 MiB).
// ---------------------------------------------------------------------------
extern "C" void kernel_launch(void* const* d_in, const int* in_sizes, int n_in,
                              void* d_out, int out_size, void* d_ws, size_t ws_size,
                              hipStream_t stream)
{
    const float* x      = (const float*)d_in[0];
    const float* n1w    = (const float*)d_in[1];
    const float* n1b    = (const float*)d_in[2];
    const float* qkv_w  = (const float*)d_in[3];
    const float* qkv_b  = (const float*)d_in[4];
    const float* proj_w = (const float*)d_in[5];
    const float* proj_b = (const float*)d_in[6];
    const float* rph    = (const float*)d_in[7];
    const float* rpw    = (const float*)d_in[8];
    const float* n2w    = (const float*)d_in[9];
    const float* n2b    = (const float*)d_in[10];
    const float* fc1_w  = (const float*)d_in[11];
    const float* fc1_b  = (const float*)d_in[12];
    const float* fc2_w  = (const float*)d_in[13];
    const float* fc2_b  = (const float*)d_in[14];
    float* out = (float*)d_out;

    char* ws = (char*)d_ws;
    const size_t MB = (size_t)1 << 20;
    bf16* qkv_wt  = (bf16*)(ws);
    bf16* proj_wt = (bf16*)(ws + (size_t)(3.5 * MB));
    bf16* fc1_wt  = (bf16*)(ws + 5 * MB);
    bf16* fc2_wt  = (bf16*)(ws + 10 * MB);
    bf16* bias_bf = (bf16*)(ws + (size_t)(14.5 * MB));
    bf16* xn1     = (bf16*)(ws + 15 * MB);
    bf16* att     = (bf16*)(ws + 15 * MB);
    bf16* xn2     = (bf16*)(ws + 15 * MB);
    bf16* qkvb    = (bf16*)(ws + 28 * MB);
    bf16* h       = (bf16*)(ws + 28 * MB);
    bf16* vt      = (bf16*)(ws + 64 * MB);
    float* y      = (float*)(ws + 79 * MB);

    transpose_all<<<6912, 256, 0, stream>>>(qkv_w, proj_w, fc1_w, fc2_w,
                                            qkv_wt, proj_wt, fc1_wt, fc2_wt);
    fill_kernel<<<601, 256, 0, stream>>>(qkv_b, vt, bias_bf);

    ln_kernel<<<8192, 256, 0, stream>>>(x, n1w, n1b, xn1);
    mfma_gemm<0, 128><<<dim3(18, 64), 256, 0, stream>>>(
        xn1, qkv_wt, qkv_b, qkvb, nullptr, nullptr, nullptr, vt, 8192, 2304, 768);
    attn_kernel<<<600, 256, 0, stream>>>(qkvb, vt, bias_bf, rph, rpw, att);
    mfma_gemm<1, 64><<<dim3(6, 128), 256, 0, stream>>>(
        att, proj_wt, proj_b, nullptr, y, x, nullptr, nullptr, 8192, 768, 768);
    ln_kernel<<<8192, 256, 0, stream>>>(y, n2w, n2b, xn2);
    mfma_gemm<2, 128><<<dim3(24, 64), 256, 0, stream>>>(
        xn2, fc1_wt, fc1_b, h, nullptr, nullptr, nullptr, nullptr, 8192, 3072, 768);
    mfma_gemm<3, 64><<<dim3(6, 128), 256, 0, stream>>>(
        h, fc2_wt, fc2_b, nullptr, out, nullptr, y, nullptr, 8192, 768, 3072);
}

// Round 7
// 405.376 us; speedup vs baseline: 6.4021x; 1.0484x over previous
//
#include <hip/hip_runtime.h>
#include <hip/hip_bf16.h>
#include <math.h>

typedef __hip_bfloat16 bf16;
typedef __attribute__((ext_vector_type(8))) short short8;
typedef __attribute__((ext_vector_type(4))) float f32x4;

__device__ __forceinline__ float b2f(bf16 v) { return __bfloat162float(v); }
__device__ __forceinline__ bf16 f2b(float f) { return __float2bfloat16(f); }

// ---------------------------------------------------------------------------
// K0: all 4 weight transposes (fp32 KxN -> bf16 NxK) in one launch.
// ---------------------------------------------------------------------------
__launch_bounds__(256)
__global__ void transpose_all(const float* __restrict__ qkv_w,
                              const float* __restrict__ proj_w,
                              const float* __restrict__ fc1_w,
                              const float* __restrict__ fc2_w,
                              bf16* __restrict__ qkv_wt,
                              bf16* __restrict__ proj_wt,
                              bf16* __restrict__ fc1_wt,
                              bf16* __restrict__ fc2_wt)
{
    __shared__ float t[32][33];
    int id = blockIdx.x;
    const float* W; bf16* Wt; int K, N, tix, tiy;
    if (id < 1728)      { W = qkv_w;  Wt = qkv_wt;  K = 768;  N = 2304; tix = id % 72;           tiy = id / 72; }
    else if (id < 2304) { W = proj_w; Wt = proj_wt; K = 768;  N = 768;  tix = (id - 1728) % 24;  tiy = (id - 1728) / 24; }
    else if (id < 4608) { W = fc1_w;  Wt = fc1_wt;  K = 768;  N = 3072; tix = (id - 2304) % 96;  tiy = (id - 2304) / 96; }
    else                { W = fc2_w;  Wt = fc2_wt;  K = 3072; N = 768;  tix = (id - 4608) % 24;  tiy = (id - 4608) / 24; }
    int n0 = tix * 32, k0 = tiy * 32;
    int tx = threadIdx.x & 31, ty = threadIdx.x >> 5;   // 32 x 8
    #pragma unroll
    for (int i = 0; i < 4; i++)
        t[ty * 4 + i][tx] = W[(size_t)(k0 + ty * 4 + i) * N + n0 + tx];
    __syncthreads();
    #pragma unroll
    for (int i = 0; i < 4; i++)
        Wt[(size_t)(n0 + ty * 4 + i) * K + k0 + tx] = f2b(t[tx][ty * 4 + i]);
}

// ---------------------------------------------------------------------------
// K0b: fill vt padded-key slots with v_bias; convert qkv_b -> bf16.
// ---------------------------------------------------------------------------
__launch_bounds__(256)
__global__ void fill_kernel(const float* __restrict__ qkv_b,
                            bf16* __restrict__ vt,
                            bf16* __restrict__ bias_bf)
{
    int blk = blockIdx.x;
    int tid = threadIdx.x;
    if (blk == 600) {
        for (int c = tid; c < 2304; c += 256) bias_bf[c] = f2b(qkv_b[c]);
        return;
    }
    int bwi = blk / 12, head = blk % 12;
    int wq = bwi % 25;
    int hi = ((wq / 5) == 4) ? 8 : 14;
    int wi = ((wq % 5) == 4) ? 8 : 14;
    if (hi == 14 && wi == 14) return;
    size_t base = (size_t)(bwi * 12 + head) * 64 * 196;
    for (int t = tid; t < 196 * 64; t += 256) {
        int d = t & 63, key = t >> 6;
        int i = key / 14, j = key % 14;
        if (i >= hi || j >= wi)
            vt[base + (size_t)d * 196 + key] = f2b(qkv_b[1536 + head * 64 + d]);
    }
}

// ---------------------------------------------------------------------------
// K1/K5: LayerNorm (fp32 in, 768 cols) -> bf16 out.
// ---------------------------------------------------------------------------
__launch_bounds__(256)
__global__ void ln_kernel(const float* __restrict__ y,
                          const float* __restrict__ wgt,
                          const float* __restrict__ bia,
                          bf16* __restrict__ xn)
{
    int blk = blockIdx.x;
    const float* yin = y + (size_t)blk * 768;
    bf16* out = xn + (size_t)blk * 768;
    int tid = threadIdx.x;
    float v[3]; float s = 0.f, ss = 0.f;
    #pragma unroll
    for (int t = 0; t < 3; t++) {
        float f = yin[tid + t * 256];
        v[t] = f; s += f; ss += f * f;
    }
    #pragma unroll
    for (int o = 32; o > 0; o >>= 1) { s += __shfl_xor(s, o); ss += __shfl_xor(ss, o); }
    __shared__ float red[8];
    int w = tid >> 6, lane = tid & 63;
    if (lane == 0) { red[w] = s; red[4 + w] = ss; }
    __syncthreads();
    s  = red[0] + red[1] + red[2] + red[3];
    ss = red[4] + red[5] + red[6] + red[7];
    float mu = s * (1.0f / 768.0f);
    float var = ss * (1.0f / 768.0f) - mu * mu;
    float rs = rsqrtf(var + 1e-5f);
    #pragma unroll
    for (int t = 0; t < 3; t++) {
        int c = tid + t * 256;
        out[c] = f2b((v[t] - mu) * rs * wgt[c] + bia[c]);
    }
}

// ---------------------------------------------------------------------------
// MFMA GEMM: C = A(M x K) @ Bt^T + bias.  BK=64 (two BK=32 LDS buffers).
// XCD-aware swizzle: x-siblings of an M-tile mapped to f === const (mod 8)
// so the shared A-tile stays in ONE XCD's L2.  gridDim.y must be %8==0.
//  EPI 0: qkv  EPI 1: proj  EPI 2: fc1+GELU  EPI 3: fc2
// ---------------------------------------------------------------------------
template<int EPI, int BM>
__launch_bounds__(256)
__global__ void mfma_gemm(const bf16* __restrict__ A,
                          const bf16* __restrict__ Bt,
                          const float* __restrict__ bias,
                          bf16* __restrict__ outb,
                          float* __restrict__ outf,
                          const float* __restrict__ xres,
                          const float* __restrict__ yres,
                          bf16* __restrict__ vtg,
                          int M, int N, int K)
{
    constexpr int MI = BM / 32;          // m-frags per wave
    __shared__ bf16 As0[BM * 32];
    __shared__ bf16 As1[BM * 32];
    __shared__ bf16 Bs0[128 * 32];
    __shared__ bf16 Bs1[128 * 32];
    const int tid = threadIdx.x;
    const int w = tid >> 6, lane = tid & 63;
    const int cl = lane & 15, rg = lane >> 4;
    const int wm = (w & 1) * (BM / 2), wn = (w >> 1) * 64;

    // XCD swizzle: all gx x-siblings of one M-tile share f%8 -> same XCD
    const int gx = gridDim.x;
    int f = blockIdx.x + gx * blockIdx.y;
    int g = f / (8 * gx), r8 = f % (8 * gx);
    const int tm = (g * 8 + (r8 & 7)) * BM;
    const int tn = (r8 >> 3) * 128;

    f32x4 acc[MI][4] = {};

    for (int k0 = 0; k0 < K; k0 += 64) {
        #pragma unroll
        for (int i = 0; i < BM / 64; i++) {
            int e = i * 256 + tid;
            int r = e >> 2, ch = e & 3;
            const bf16* ap = A + (size_t)(tm + r) * K + k0 + ch * 8;
            __builtin_amdgcn_global_load_lds(
                (const __attribute__((address_space(1))) unsigned*)(ap),
                (__attribute__((address_space(3))) unsigned*)(As0 + e * 8), 16, 0, 0);
            __builtin_amdgcn_global_load_lds(
                (const __attribute__((address_space(1))) unsigned*)(ap + 32),
                (__attribute__((address_space(3))) unsigned*)(As1 + e * 8), 16, 0, 0);
        }
        #pragma unroll
        for (int i = 0; i < 2; i++) {
            int e = i * 256 + tid;
            int r = e >> 2, ch = e & 3;
            const bf16* bp = Bt + (size_t)(tn + r) * K + k0 + ch * 8;
            __builtin_amdgcn_global_load_lds(
                (const __attribute__((address_space(1))) unsigned*)(bp),
                (__attribute__((address_space(3))) unsigned*)(Bs0 + e * 8), 16, 0, 0);
            __builtin_amdgcn_global_load_lds(
                (const __attribute__((address_space(1))) unsigned*)(bp + 32),
                (__attribute__((address_space(3))) unsigned*)(Bs1 + e * 8), 16, 0, 0);
        }
        __syncthreads();
        #pragma unroll
        for (int kk = 0; kk < 2; kk++) {
            const bf16* Ab = kk ? As1 : As0;
            const bf16* Bb = kk ? Bs1 : Bs0;
            short8 af[MI], bfr[4];
            #pragma unroll
            for (int mi = 0; mi < MI; mi++)
                af[mi] = *(const short8*)(Ab + (wm + mi * 16 + cl) * 32 + rg * 8);
            #pragma unroll
            for (int ni = 0; ni < 4; ni++)
                bfr[ni] = *(const short8*)(Bb + (wn + ni * 16 + cl) * 32 + rg * 8);
            #pragma unroll
            for (int mi = 0; mi < MI; mi++)
                #pragma unroll
                for (int ni = 0; ni < 4; ni++)
                    acc[mi][ni] = __builtin_amdgcn_mfma_f32_16x16x32_bf16(
                        af[mi], bfr[ni], acc[mi][ni], 0, 0, 0);
        }
        __syncthreads();
    }

    const int row_l = rg * 4;
    float bv[4];
    #pragma unroll
    for (int ni = 0; ni < 4; ni++) bv[ni] = bias[tn + wn + ni * 16 + cl];

    #pragma unroll
    for (int mi = 0; mi < MI; mi++) {
        #pragma unroll
        for (int r = 0; r < 4; r++) {
            int gm = tm + wm + mi * 16 + row_l + r;
            if (EPI == 0) {
                int bb = gm >> 12, rr = (gm >> 6) & 63, cc = gm & 63;
                int wh = rr / 14, ii = rr - wh * 14;
                int ww2 = cc / 14, jj = cc - ww2 * 14;
                size_t vrow = (size_t)((bb * 25 + wh * 5 + ww2) * 12) * 64;
                int key = ii * 14 + jj;
                #pragma unroll
                for (int ni = 0; ni < 4; ni++) {
                    int gn = tn + wn + ni * 16 + cl;
                    float v = acc[mi][ni][r] + bv[ni];
                    if (gn < 1536) {
                        outb[(size_t)gm * 2304 + gn] = f2b(v);
                    } else {
                        int hv = gn - 1536;
                        vtg[(vrow + ((hv >> 6) * 64 + (hv & 63))) * 196 + key] = f2b(v);
                    }
                }
            } else if (EPI == 1) {
                #pragma unroll
                for (int ni = 0; ni < 4; ni++) {
                    int gn = tn + wn + ni * 16 + cl;
                    outf[(size_t)gm * 768 + gn] =
                        xres[(size_t)gm * 768 + gn] + acc[mi][ni][r] + bv[ni];
                }
            } else if (EPI == 2) {
                #pragma unroll
                for (int ni = 0; ni < 4; ni++) {
                    int gn = tn + wn + ni * 16 + cl;
                    float v = acc[mi][ni][r] + bv[ni];
                    outb[(size_t)gm * N + gn] =
                        f2b(0.5f * v * (1.0f + erff(v * 0.70710678118654752f)));
                }
            } else {
                #pragma unroll
                for (int ni = 0; ni < 4; ni++) {
                    int gn = tn + wn + ni * 16 + cl;
                    outf[(size_t)gm * 768 + gn] =
                        yres[(size_t)gm * 768 + gn] + acc[mi][ni][r] + bv[ni];
                }
            }
        }
    }
}

// ---------------------------------------------------------------------------
// K3: fused MFMA windowed attention (unchanged, verified).
// ---------------------------------------------------------------------------
__launch_bounds__(256)
__global__ void attn_kernel(const bf16* __restrict__ qkv,
                            const bf16* __restrict__ vtg,
                            const bf16* __restrict__ bias_bf,
                            const float* __restrict__ rel_h,
                            const float* __restrict__ rel_w,
                            bf16* __restrict__ att)
{
    __shared__ bf16 BsLo[272 * 32];
    __shared__ bf16 BsHi[272 * 32];
    __shared__ bf16 Vt[64 * 232];
    __shared__ bf16 Ps[4][16 * 36];
    __shared__ bf16 relS[4][2][16 * 32];

    int bh = blockIdx.x;
    int bwi = bh / 12, head = bh % 12;
    int tid = threadIdx.x, w = tid >> 6, lane = tid & 63;
    int b = bwi / 25, wq = bwi % 25;
    int r0 = (wq / 5) * 14, c0 = (wq % 5) * 14;

    for (int idx = tid; idx < 76 * 16; idx += 256) {
        int r = 196 + (idx >> 4), cd = idx & 15;
        ((unsigned*)BsLo)[r * 16 + cd] = 0u;
        ((unsigned*)BsHi)[r * 16 + cd] = 0u;
    }
    for (int idx = tid; idx < 196 * 32; idx += 256) {
        int m = idx >> 5, c2 = idx & 31;
        int i = m / 14, j = m % 14;
        int rr = r0 + i, cc = c0 + j;
        const bf16* src = (rr < 64 && cc < 64)
            ? qkv + ((size_t)((b << 12) + rr * 64 + cc) * 2304 + 768 + head * 64)
            : bias_bf + 768 + head * 64;
        unsigned u = *(const unsigned*)(src + 2 * c2);
        if (c2 < 16) ((unsigned*)BsLo)[m * 16 + c2] = u;
        else         ((unsigned*)BsHi)[m * 16 + (c2 - 16)] = u;
    }
    for (int idx = tid; idx < 27 * 32; idx += 256) {
        int t = idx >> 5, c2 = idx & 31;
        float2 h2 = *(const float2*)(rel_h + t * 64 + 2 * c2);
        float2 w2 = *(const float2*)(rel_w + t * 64 + 2 * c2);
        bf16 hb[2] = { f2b(h2.x), f2b(h2.y) };
        bf16 wb[2] = { f2b(w2.x), f2b(w2.y) };
        int r1 = 208 + t, r2 = 240 + t;
        if (c2 < 16) {
            ((unsigned*)BsLo)[r1 * 16 + c2] = *(unsigned*)hb;
            ((unsigned*)BsLo)[r2 * 16 + c2] = *(unsigned*)wb;
        } else {
            ((unsigned*)BsHi)[r1 * 16 + c2 - 16] = *(unsigned*)hb;
            ((unsigned*)BsHi)[r2 * 16 + c2 - 16] = *(unsigned*)wb;
        }
    }
    for (int idx = tid; idx < 64 * 18; idx += 256) {
        int d = idx / 18, cd = idx % 18;
        ((unsigned*)Vt)[d * 116 + 98 + cd] = 0u;
    }
    {
        const bf16* vrow = vtg + (size_t)(bwi * 12 + head) * 64 * 196;
        for (int idx = tid; idx < 64 * 98; idx += 256) {
            int d = idx / 98, kp = idx % 98;
            ((unsigned*)Vt)[d * 116 + kp] = *(const unsigned*)(vrow + (size_t)d * 196 + 2 * kp);
        }
    }
    __syncthreads();

    const int cl = lane & 15, rg = lane >> 4;
    const int lr0 = rg * 4;

    for (int mt = w; mt < 13; mt += 4) {
        int q0 = mt * 16 + cl;
        int qi = q0 / 14, qj = q0 % 14;
        int qr = r0 + qi, qc = c0 + qj;
        bool qv = (q0 < 196) && (qr < 64) && (qc < 64);
        const bf16* qp = qv
            ? qkv + ((size_t)((b << 12) + qr * 64 + qc) * 2304 + head * 64 + rg * 8)
            : bias_bf + head * 64 + rg * 8;
        short8 af0 = *(const short8*)(qp);
        short8 af1 = *(const short8*)(qp + 32);

        f32x4 sc[17];
        #pragma unroll
        for (int ni = 0; ni < 17; ni++) {
            short8 blo = *(const short8*)(BsLo + (ni * 16 + cl) * 32 + rg * 8);
            short8 bhi = *(const short8*)(BsHi + (ni * 16 + cl) * 32 + rg * 8);
            f32x4 t = {};
            t = __builtin_amdgcn_mfma_f32_16x16x32_bf16(af0, blo, t, 0, 0, 0);
            sc[ni] = __builtin_amdgcn_mfma_f32_16x16x32_bf16(af1, bhi, t, 0, 0, 0);
        }
        #pragma unroll
        for (int t = 0; t < 2; t++)
            #pragma unroll
            for (int r = 0; r < 4; r++) {
                relS[w][0][(lr0 + r) * 32 + t * 16 + cl] = f2b(sc[13 + t][r]);
                relS[w][1][(lr0 + r) * 32 + t * 16 + cl] = f2b(sc[15 + t][r]);
            }
        __builtin_amdgcn_wave_barrier();

        int iq[4], jq[4];
        #pragma unroll
        for (int r = 0; r < 4; r++) { int q = mt * 16 + lr0 + r; iq[r] = q / 14; jq[r] = q % 14; }
        float mx[4] = { -1e30f, -1e30f, -1e30f, -1e30f };
        #pragma unroll
        for (int ni = 0; ni < 13; ni++) {
            int c = ni * 16 + cl;
            int kh = c / 14; if (kh > 13) kh = 13;
            int kw = c - (c / 14) * 14;
            bool valid = c < 196;
            #pragma unroll
            for (int r = 0; r < 4; r++) {
                float lg = sc[ni][r] * 0.125f
                         + b2f(relS[w][0][(lr0 + r) * 32 + iq[r] - kh + 13])
                         + b2f(relS[w][1][(lr0 + r) * 32 + jq[r] - kw + 13]);
                sc[ni][r] = valid ? lg : -1e30f;
                mx[r] = fmaxf(mx[r], sc[ni][r]);
            }
        }
        float sum[4];
        #pragma unroll
        for (int r = 0; r < 4; r++) {
            #pragma unroll
            for (int o = 1; o < 16; o <<= 1) mx[r] = fmaxf(mx[r], __shfl_xor(mx[r], o));
            sum[r] = 0.f;
        }
        #pragma unroll
        for (int ni = 0; ni < 13; ni++)
            #pragma unroll
            for (int r = 0; r < 4; r++) {
                float e = __expf(sc[ni][r] - mx[r]);
                sc[ni][r] = e; sum[r] += e;
            }
        #pragma unroll
        for (int r = 0; r < 4; r++) {
            #pragma unroll
            for (int o = 1; o < 16; o <<= 1) sum[r] += __shfl_xor(sum[r], o);
            sum[r] = 1.0f / sum[r];
        }

        f32x4 ov[4] = {};
        #pragma unroll
        for (int ks = 0; ks < 7; ks++) {
            #pragma unroll
            for (int r = 0; r < 4; r++) {
                Ps[w][(lr0 + r) * 36 + cl] = f2b(sc[2 * ks][r] * sum[r]);
                Ps[w][(lr0 + r) * 36 + 16 + cl] =
                    (2 * ks + 1 < 13) ? f2b(sc[2 * ks + 1][r] * sum[r]) : f2b(0.0f);
            }
            __builtin_amdgcn_wave_barrier();
            short8 pa = *(const short8*)(&Ps[w][cl * 36 + rg * 8]);
            #pragma unroll
            for (int ni = 0; ni < 4; ni++) {
                short8 vb = *(const short8*)(Vt + (ni * 16 + cl) * 232 + ks * 32 + rg * 8);
                ov[ni] = __builtin_amdgcn_mfma_f32_16x16x32_bf16(pa, vb, ov[ni], 0, 0, 0);
            }
            __builtin_amdgcn_wave_barrier();
        }

        #pragma unroll
        for (int r = 0; r < 4; r++) {
            int q = mt * 16 + lr0 + r;
            int i = q / 14, j = q % 14;
            int rr = r0 + i, cc = c0 + j;
            if (q < 196 && rr < 64 && cc < 64) {
                size_t ob = (size_t)((b << 12) + rr * 64 + cc) * 768 + head * 64;
                #pragma unroll
                for (int ni = 0; ni < 4; ni++)
                    att[ob + ni * 16 + cl] = f2b(ov[ni][r]);
            }
        }
    }
}

// ---------------------------------------------------------------------------
// Workspace layout unchanged (peak ~104 MiB).
// ---------------------------------------------------------------------------
extern "C" void kernel_launch(void* const* d_in, const int* in_sizes, int n_in,
                              void* d_out, int out_size, void* d_ws, size_t ws_size,
                              hipStream_t stream)
{
    const float* x      = (const float*)d_in[0];
    const float* n1w    = (const float*)d_in[1];
    const float* n1b    = (const float*)d_in[2];
    const float* qkv_w  = (const float*)d_in[3];
    const float* qkv_b  = (const float*)d_in[4];
    const float* proj_w = (const float*)d_in[5];
    const float* proj_b = (const float*)d_in[6];
    const float* rph    = (const float*)d_in[7];
    const float* rpw    = (const float*)d_in[8];
    const float* n2w    = (const float*)d_in[9];
    const float* n2b    = (const float*)d_in[10];
    const float* fc1_w  = (const float*)d_in[11];
    const float* fc1_b  = (const float*)d_in[12];
    const float* fc2_w  = (const float*)d_in[13];
    const float* fc2_b  = (const float*)d_in[14];
    float* out = (float*)d_out;

    char* ws = (char*)d_ws;
    const size_t MB = (size_t)1 << 20;
    bf16* qkv_wt  = (bf16*)(ws);
    bf16* proj_wt = (bf16*)(ws + (size_t)(3.5 * MB));
    bf16* fc1_wt  = (bf16*)(ws + 5 * MB);
    bf16* fc2_wt  = (bf16*)(ws + 10 * MB);
    bf16* bias_bf = (bf16*)(ws + (size_t)(14.5 * MB));
    bf16* xn1     = (bf16*)(ws + 15 * MB);
    bf16* att     = (bf16*)(ws + 15 * MB);
    bf16* xn2     = (bf16*)(ws + 15 * MB);
    bf16* qkvb    = (bf16*)(ws + 28 * MB);
    bf16* h       = (bf16*)(ws + 28 * MB);
    bf16* vt      = (bf16*)(ws + 64 * MB);
    float* y      = (float*)(ws + 79 * MB);

    transpose_all<<<6912, 256, 0, stream>>>(qkv_w, proj_w, fc1_w, fc2_w,
                                            qkv_wt, proj_wt, fc1_wt, fc2_wt);
    fill_kernel<<<601, 256, 0, stream>>>(qkv_b, vt, bias_bf);

    ln_kernel<<<8192, 256, 0, stream>>>(x, n1w, n1b, xn1);
    mfma_gemm<0, 128><<<dim3(18, 64), 256, 0, stream>>>(
        xn1, qkv_wt, qkv_b, qkvb, nullptr, nullptr, nullptr, vt, 8192, 2304, 768);
    attn_kernel<<<600, 256, 0, stream>>>(qkvb, vt, bias_bf, rph, rpw, att);
    mfma_gemm<1, 64><<<dim3(6, 128), 256, 0, stream>>>(
        att, proj_wt, proj_b, nullptr, y, x, nullptr, nullptr, 8192, 768, 768);
    ln_kernel<<<8192, 256, 0, stream>>>(y, n2w, n2b, xn2);
    mfma_gemm<2, 128><<<dim3(24, 64), 256, 0, stream>>>(
        xn2, fc1_wt, fc1_b, h, nullptr, nullptr, nullptr, nullptr, 8192, 3072, 768);
    mfma_gemm<3, 64><<<dim3(6, 128), 256, 0, stream>>>(
        h, fc2_wt, fc2_b, nullptr, out, nullptr, y, nullptr, 8192, 768, 3072);
}